// Round 1
// 1819.754 us; speedup vs baseline: 1.2744x; 1.2744x over previous
//
#include <hip/hip_runtime.h>
#include <stdint.h>

// GlobalAttention fused pipeline, MI355X gfx950.
// Round 5: k_attn's qkv 1x1-conv (51.5 GFLOP, 86% of its FMAs) moved to MFMA.
//   K0: wx,wy -> WT bf16 [2][8][256][256]; wqkv -> bf16 [768][256]  @ d_ws
//   K1: x -> LDS [px][c] bf16 once; MFMA GEMM (M=768,N=64,K=256) -> q/k/v LDS;
//       VALU attention (unchanged math) -> o NHWC bf16 (first half of d_out)
//   K2: o,WT -> out1 NCHW bf16 (second half of d_out arena)  [MFMA]
//   K3: out1 -> bn NCHW bf16 @ d_ws (overwrites dead WT)
//   K4: bn -> d_out f32 final

#define B_ 2
#define C_ 256
#define H_ 256
#define W_ 256
#define HW_ 65536

typedef unsigned short u16;
typedef unsigned int u32;
typedef short bf16x8 __attribute__((ext_vector_type(8)));
typedef float f32x16 __attribute__((ext_vector_type(16)));

__device__ __forceinline__ float b2f(u16 h) {
  union { u32 u; float f; } x; x.u = ((u32)h) << 16; return x.f;
}
__device__ __forceinline__ float b2f_lo(u32 u) {
  union { u32 v; float f; } x; x.v = u << 16; return x.f;
}
__device__ __forceinline__ float b2f_hi(u32 u) {
  union { u32 v; float f; } x; x.v = u & 0xffff0000u; return x.f;
}
__device__ __forceinline__ u16 f2b(float f) {  // RNE
  union { float f; u32 u; } x; x.f = f;
  return (u16)((x.u + 0x7fffu + ((x.u >> 16) & 1u)) >> 16);
}
__device__ __forceinline__ u32 pack2(float a, float b) {
  return (u32)f2b(a) | ((u32)f2b(b) << 16);
}

// ---------------------------------------------------------------------------
// K0: weight transpose  wx/wy [o][c][t] f32  ->  WT bf16 [conv][t][o][c]
//     + wqkv f32 [768][256] -> bf16 [768][256] (K-contiguous, A-operand ready)
// ---------------------------------------------------------------------------
__global__ __launch_bounds__(256) void k_wt(
    const float* __restrict__ wx, const float* __restrict__ wy,
    const float* __restrict__ wqkv, u16* __restrict__ wt)
{
  const int o = blockIdx.x, c = threadIdx.x;
  const float* px = wx + ((size_t)o * 256 + c) * 8;
  const float* py = wy + ((size_t)o * 256 + c) * 8;
#pragma unroll
  for (int t = 0; t < 8; ++t) {
    wt[(size_t)t * 65536 + o * 256 + c]          = f2b(px[t]);
    wt[524288 + (size_t)t * 65536 + o * 256 + c] = f2b(py[t]);
  }
  u16* w8 = wt + 1048576;
#pragma unroll
  for (int t = 0; t < 3; ++t) {
    const int row = o + t * 256;
    w8[(size_t)row * 256 + c] = f2b(wqkv[(size_t)row * 256 + c]);
  }
}

// ---------------------------------------------------------------------------
// K1: qkv (1x1 conv via MFMA) + windowed attention. One block per 8x8 window.
// Output o written NHWC bf16: o[b][h][w][c].
// LDS: xb [64px][264c] bf16 (B-operand, K-contig; union with softmax sc)
//      q_l/k_l [256ch][68px] bf16, vt_l [64px][268ch] bf16.  ~134.5 KiB total.
// ---------------------------------------------------------------------------
__global__ __launch_bounds__(256) void k_attn(
    const float* __restrict__ x, const u16* __restrict__ w8,
    const float* __restrict__ rel, u16* __restrict__ o_img)
{
  __shared__ __align__(16) union {
    u16 xb[64][264];                                    // 33792 B (phase 1-2)
    struct { float sc[64][68]; float rsum[64]; } s3;    // 17664 B (phase 3)
  } U;
  __shared__ __align__(16) u16 q_l[256][68];            // 34816 B
  __shared__ __align__(16) u16 k_l[256][68];            // 34816 B
  __shared__ __align__(16) u16 vt_l[64][268];           // 34304 B

  const int tid = threadIdx.x;
  const int nb  = blockIdx.x;
  const int b   = nb >> 10;
  const int hh  = (nb >> 5) & 31;
  const int ww  = nb & 31;
  const int h0  = hh << 3, w0 = ww << 3;

  // ---- phase 1: stage x window -> LDS [px][c] bf16 (x read ONCE) ----
  {
    const int c2 = tid & 127;       // channel pair index
    const int half = tid >> 7;      // which 4 rows
    const float* p0 = x + (((size_t)(b * C_ + 2 * c2)) * H_ + (h0 + half * 4)) * W_ + w0;
    const float* p1 = p0 + (size_t)H_ * W_;
#pragma unroll
    for (int r = 0; r < 4; ++r) {
      const float4 a0 = *(const float4*)(p0 + r * W_);
      const float4 a1 = *(const float4*)(p0 + r * W_ + 4);
      const float4 b0 = *(const float4*)(p1 + r * W_);
      const float4 b1 = *(const float4*)(p1 + r * W_ + 4);
      const float fa[8] = {a0.x, a0.y, a0.z, a0.w, a1.x, a1.y, a1.z, a1.w};
      const float fb[8] = {b0.x, b0.y, b0.z, b0.w, b1.x, b1.y, b1.z, b1.w};
      const int px0 = (half * 4 + r) * 8;
#pragma unroll
      for (int cc = 0; cc < 8; ++cc)
        *(u32*)&U.xb[px0 + cc][2 * c2] = pack2(fa[cc], fb[cc]);
    }
  }
  __syncthreads();

  // ---- phase 2: MFMA GEMM  qkv[768][64px] = w8[768][256] @ xb[256][64px] ----
  const int lane = tid & 63, wid = tid >> 6;
  const int n = lane & 31, h5 = lane >> 5;

  f32x16 acc[6][2];
#pragma unroll
  for (int mt = 0; mt < 6; ++mt)
#pragma unroll
    for (int nt = 0; nt < 2; ++nt)
#pragma unroll
      for (int i = 0; i < 16; ++i) acc[mt][nt][i] = 0.f;

#pragma unroll 2
  for (int kb = 0; kb < 16; ++kb) {
    const int k0 = kb * 16;
    bf16x8 bfr[2];
#pragma unroll
    for (int nt = 0; nt < 2; ++nt) {
      union { uint4 u; bf16x8 v; } T;
      T.u = *(const uint4*)&U.xb[nt * 32 + n][k0 + h5 * 8];
      bfr[nt] = T.v;
    }
#pragma unroll
    for (int mt = 0; mt < 6; ++mt) {
      const int row = wid * 192 + mt * 32 + n;
      union { uint4 u; bf16x8 v; } A;
      A.u = *(const uint4*)(w8 + (size_t)row * 256 + k0 + h5 * 8);
      acc[mt][0] = __builtin_amdgcn_mfma_f32_32x32x16_bf16(A.v, bfr[0], acc[mt][0], 0, 0, 0);
      acc[mt][1] = __builtin_amdgcn_mfma_f32_32x32x16_bf16(A.v, bfr[1], acc[mt][1], 0, 0, 0);
    }
  }

  // ---- phase 2.5: scatter acc -> q_l [ch][px], k_l [ch][px], vt_l [px][ch] ----
#pragma unroll
  for (int mt = 0; mt < 6; ++mt) {
    const int rowbase = wid * 192 + mt * 32;       // wave-uniform
    const int which = rowbase >> 8;                // 0=q, 1=k, 2=v
    const int chb = (rowbase & 255) + 4 * h5;
#pragma unroll
    for (int nt = 0; nt < 2; ++nt) {
      const int px = nt * 32 + n;
      if (which == 2) {
#pragma unroll
        for (int rg = 0; rg < 4; ++rg) {
          const int ch = chb + rg * 8;
          *(u32*)&vt_l[px][ch]     = pack2(acc[mt][nt][rg * 4 + 0], acc[mt][nt][rg * 4 + 1]);
          *(u32*)&vt_l[px][ch + 2] = pack2(acc[mt][nt][rg * 4 + 2], acc[mt][nt][rg * 4 + 3]);
        }
      } else {
        u16 (*dst)[68] = (which == 0) ? q_l : k_l;
#pragma unroll
        for (int r = 0; r < 16; ++r) {
          const int ch = chb + (r & 3) + 8 * (r >> 2);
          dst[ch][px] = f2b(acc[mt][nt][r]);
        }
      }
    }
  }
  __syncthreads();

  // ---- phase 3: per-head attention (VALU, math unchanged) ----
  for (int head = 0; head < 16; ++head) {
    const int hb = head << 4;
    {
      const int ti = tid >> 4, tj = tid & 15;
      const int i0 = ti * 4, j0 = tj * 4;
      float dd_[4][4];
#pragma unroll
      for (int a = 0; a < 4; ++a)
#pragma unroll
        for (int bb = 0; bb < 4; ++bb) dd_[a][bb] = 0.f;
#pragma unroll
      for (int dd = 0; dd < 16; ++dd) {
        const uint2 qv = *(const uint2*)&q_l[hb + dd][i0];
        const uint2 kv = *(const uint2*)&k_l[hb + dd][j0];
        const float fq[4] = {b2f_lo(qv.x), b2f_hi(qv.x), b2f_lo(qv.y), b2f_hi(qv.y)};
        const float fk[4] = {b2f_lo(kv.x), b2f_hi(kv.x), b2f_lo(kv.y), b2f_hi(kv.y)};
#pragma unroll
        for (int a = 0; a < 4; ++a)
#pragma unroll
          for (int bb = 0; bb < 4; ++bb) dd_[a][bb] += fq[a] * fk[bb];
      }
#pragma unroll
      for (int a = 0; a < 4; ++a) {
        const int i = i0 + a, iy = i >> 3, ix = i & 7;
        float t4[4];
#pragma unroll
        for (int bb = 0; bb < 4; ++bb) {
          const int j = j0 + bb, jy = j >> 3, jx = j & 7;
          const int ridx = (iy - jy + 7) * 15 + (ix - jx + 7);
          t4[bb] = dd_[a][bb] * 0.25f + rel[ridx * 16 + head];
        }
        float4 sv; sv.x = t4[0]; sv.y = t4[1]; sv.z = t4[2]; sv.w = t4[3];
        *(float4*)&U.s3.sc[i][j0] = sv;
      }
    }
    __syncthreads();
    if (tid < 64) {
      float m = -1e30f;
      for (int j = 0; j < 64; j += 4) {
        const float4 v = *(const float4*)&U.s3.sc[tid][j];
        m = fmaxf(m, fmaxf(fmaxf(v.x, v.y), fmaxf(v.z, v.w)));
      }
      float s = 0.f;
      for (int j = 0; j < 64; j += 4) {
        float4 v = *(float4*)&U.s3.sc[tid][j];
        v.x = __expf(v.x - m); v.y = __expf(v.y - m);
        v.z = __expf(v.z - m); v.w = __expf(v.w - m);
        s += v.x + v.y + v.z + v.w;
        *(float4*)&U.s3.sc[tid][j] = v;
      }
      U.s3.rsum[tid] = 1.0f / s;
    }
    __syncthreads();
    {
      const int i = tid >> 2, dg = tid & 3;
      float a0 = 0.f, a1 = 0.f, a2 = 0.f, a3 = 0.f;
      for (int j = 0; j < 64; ++j) {
        const float p = U.s3.sc[i][j];
        const uint2 vv = *(const uint2*)&vt_l[j][hb + dg * 4];
        a0 += p * b2f_lo(vv.x);
        a1 += p * b2f_hi(vv.x);
        a2 += p * b2f_lo(vv.y);
        a3 += p * b2f_hi(vv.y);
      }
      const float r = U.s3.rsum[i];
      const int ch = hb + dg * 4;
      const int iy = i >> 3, ix = i & 7;
      u16* op = o_img + (((size_t)(b * H_ + h0 + iy)) * W_ + (w0 + ix)) * C_ + ch;
      *(u32*)op       = pack2(a0 * r, a1 * r);
      *(u32*)(op + 2) = pack2(a2 * r, a3 * r);
    }
    __syncthreads();
  }
}

// ---------------------------------------------------------------------------
// K2 (MFMA): out1 = ox + oy + bx + by.
// ---------------------------------------------------------------------------
__global__ __launch_bounds__(256) void k_conv2m(
    const u16* __restrict__ o_nhwc, const u16* __restrict__ wt,
    const float* __restrict__ bxg, const float* __restrict__ byg,
    u16* __restrict__ out1)
{
  __shared__ u16 tile[8 * 136 * 20];   // 43.5 KB
  __shared__ float bias_l[128];

  const int tid = threadIdx.x, nb = blockIdx.x;
  const int wh = nb & 1, oh = (nb >> 1) & 1, h = (nb >> 2) & 255, b = nb >> 10;
  const int ob = oh * 128, wb0 = wh * 128;
  const int lane = tid & 63, wid = tid >> 6;
  const int wo = (wid >> 1) * 64, wwv = (wid & 1) * 64;
  const int n = lane & 31, h5 = lane >> 5;

  if (tid < 128) bias_l[tid] = bxg[ob + tid] + byg[ob + tid];

  f32x16 acc[2][2];
#pragma unroll
  for (int mt = 0; mt < 2; ++mt)
#pragma unroll
    for (int nt = 0; nt < 2; ++nt)
#pragma unroll
      for (int i = 0; i < 16; ++i) acc[mt][nt][i] = 0.f;

  for (int cb = 0; cb < 16; ++cb) {
    const int c0 = cb * 16;
    __syncthreads();
    for (int e = tid; e < 1088; e += 256) {
      const int r = e / 136, wi = e - r * 136;
      const int hp = h - 3 + r;
      const int wp = wb0 + wi - 4;
      uint2 v0 = make_uint2(0, 0), v1 = v0, v2 = v0, v3 = v0;
      if (hp >= 0 && hp <= 256 && wp >= 0 && wp <= 256) {
        const int hr = (hp == 256) ? 254 : hp;
        const int wr = (wp == 256) ? 254 : wp;
        const u16* src = o_nhwc + (((size_t)(b * H_ + hr)) * W_ + wr) * C_ + c0;
        const uint4 A  = *(const uint4*)src;
        const uint4 Bv = *(const uint4*)(src + 8);
        v0 = make_uint2(A.x, A.y);  v1 = make_uint2(A.z, A.w);
        v2 = make_uint2(Bv.x, Bv.y); v3 = make_uint2(Bv.z, Bv.w);
      }
      u16* d = &tile[(r * 136 + wi) * 20];
      *(uint2*)(d)      = v0;
      *(uint2*)(d + 4)  = v1;
      *(uint2*)(d + 8)  = v2;
      *(uint2*)(d + 12) = v3;
    }
    __syncthreads();
#pragma unroll
    for (int cv = 0; cv < 2; ++cv) {
      const u16* wbase = wt + (size_t)cv * 524288;
#pragma unroll
      for (int t = 0; t < 8; ++t) {
        bf16x8 a[2], bb[2];
#pragma unroll
        for (int mt = 0; mt < 2; ++mt) {
          const int o = ob + wo + mt * 32 + n;
          union { uint4 u; bf16x8 v; } Uu;
          Uu.u = *(const uint4*)(wbase + ((size_t)(t * 256 + o)) * 256 + c0 + h5 * 8);
          a[mt] = Uu.v;
        }
#pragma unroll
        for (int nt = 0; nt < 2; ++nt) {
          const int rr = cv ? 3 : t;
          const int wi = wwv + nt * 32 + n + (cv ? (t + 1) : 4);
          const u16* p = &tile[(rr * 136 + wi) * 20 + h5 * 8];
          union { uint2 u[2]; bf16x8 v; } Uu;
          Uu.u[0] = *(const uint2*)p;
          Uu.u[1] = *(const uint2*)(p + 4);
          bb[nt] = Uu.v;
        }
        acc[0][0] = __builtin_amdgcn_mfma_f32_32x32x16_bf16(a[0], bb[0], acc[0][0], 0, 0, 0);
        acc[0][1] = __builtin_amdgcn_mfma_f32_32x32x16_bf16(a[0], bb[1], acc[0][1], 0, 0, 0);
        acc[1][0] = __builtin_amdgcn_mfma_f32_32x32x16_bf16(a[1], bb[0], acc[1][0], 0, 0, 0);
        acc[1][1] = __builtin_amdgcn_mfma_f32_32x32x16_bf16(a[1], bb[1], acc[1][1], 0, 0, 0);
      }
    }
  }
#pragma unroll
  for (int mt = 0; mt < 2; ++mt)
#pragma unroll
    for (int nt = 0; nt < 2; ++nt)
#pragma unroll
      for (int r = 0; r < 16; ++r) {
        const int om = wo + mt * 32 + (r & 3) + 8 * (r >> 2) + 4 * h5;
        const int o = ob + om;
        const int wg = wb0 + wwv + nt * 32 + n;
        const float v = acc[mt][nt][r] + bias_l[om];
        out1[(((size_t)(b * C_ + o)) * H_ + h) * W_ + wg] = f2b(v);
      }
}

// ---------------------------------------------------------------------------
// K3: depthwise 8x8 conv + BN (NCHW in/out, unchanged).
// ---------------------------------------------------------------------------
__global__ __launch_bounds__(256) void k_dwbn(
    const u16* __restrict__ out1, const float* __restrict__ wdw,
    const float* __restrict__ gam, const float* __restrict__ bet,
    const float* __restrict__ mea, const float* __restrict__ var,
    u16* __restrict__ bno)
{
  __shared__ u16 tile[23][264];
  const int tid = threadIdx.x, nb = blockIdx.x;
  const int c = nb & 255, ht = (nb >> 8) & 15, b = nb >> 12;
  const int h0 = ht * 16;

  for (int e = tid; e < 23 * 264; e += 256) {
    const int tr = e / 264, tc = e % 264;
    const int r = h0 - 3 + tr;
    const int cg = tc - 3;
    u16 v = 0;
    if (r >= 0 && r <= 256 && cg >= 0 && cg <= 256) {
      const int rr = (r == 256) ? 254 : r;
      const int cgm = (cg == 256) ? 254 : cg;
      v = out1[(((size_t)(b * C_ + c)) * H_ + rr) * W_ + cgm];
    }
    tile[tr][tc] = v;
  }
  float wk[64];
#pragma unroll
  for (int k2 = 0; k2 < 64; ++k2) wk[k2] = wdw[c * 64 + k2];
  const float scl = gam[c] / sqrtf(var[c] + 1e-5f);
  const float shf = bet[c] - mea[c] * scl;
  __syncthreads();

  const int wg = tid & 31, hg = tid >> 5;
  const int w0 = wg * 8;
#pragma unroll
  for (int k = 0; k < 2; ++k) {
    const int hl = hg * 2 + k;
    float a[8];
#pragma unroll
    for (int s = 0; s < 8; ++s) a[s] = 0.f;
#pragma unroll
    for (int i = 0; i < 8; ++i) {
      const uint4 va = *(const uint4*)&tile[hl + i][w0];
      const uint4 vb = *(const uint4*)&tile[hl + i][w0 + 8];
      float f[16];
      f[0] = b2f_lo(va.x);  f[1] = b2f_hi(va.x);  f[2] = b2f_lo(va.y);  f[3] = b2f_hi(va.y);
      f[4] = b2f_lo(va.z);  f[5] = b2f_hi(va.z);  f[6] = b2f_lo(va.w);  f[7] = b2f_hi(va.w);
      f[8] = b2f_lo(vb.x);  f[9] = b2f_hi(vb.x);  f[10] = b2f_lo(vb.y); f[11] = b2f_hi(vb.y);
      f[12] = b2f_lo(vb.z); f[13] = b2f_hi(vb.z); f[14] = b2f_lo(vb.w); f[15] = b2f_hi(vb.w);
#pragma unroll
      for (int j = 0; j < 8; ++j) {
        const float wv = wk[i * 8 + j];
#pragma unroll
        for (int s = 0; s < 8; ++s) a[s] += f[s + j] * wv;
      }
    }
    uint4 uv;
    uv.x = pack2(a[0] * scl + shf, a[1] * scl + shf);
    uv.y = pack2(a[2] * scl + shf, a[3] * scl + shf);
    uv.z = pack2(a[4] * scl + shf, a[5] * scl + shf);
    uv.w = pack2(a[6] * scl + shf, a[7] * scl + shf);
    *(uint4*)&bno[(((size_t)(b * C_ + c)) * H_ + h0 + hl) * W_ + w0] = uv;
  }
}

// ---------------------------------------------------------------------------
// K4: 1x1 projection (unchanged). Output FLOAT32.
// ---------------------------------------------------------------------------
__global__ __launch_bounds__(256) void k_proj(
    const u16* __restrict__ bno, const float* __restrict__ wp, float* __restrict__ out)
{
  __shared__ u16 bn[256][72];
  __shared__ u16 wpT[32][264];
  const int tid = threadIdx.x, nb = blockIdx.x;
  const int wtile = nb & 3, h = (nb >> 2) & 255, b = nb >> 10;
  const int w0 = wtile * 64;
  const int og = tid >> 3, pg = tid & 7;

  for (int k = 0; k < 8; ++k) {
    const int e = tid + k * 256;
    const int cc2 = e >> 3, seg = e & 7;
    *(uint4*)&bn[cc2][seg * 8] =
        *(const uint4*)&bno[(((size_t)(b * C_ + cc2)) * H_ + h) * W_ + w0 + seg * 8];
  }
  float acc[8][8];
#pragma unroll
  for (int a = 0; a < 8; ++a)
#pragma unroll
    for (int s = 0; s < 8; ++s) acc[a][s] = 0.f;

  for (int cb = 0; cb < 8; ++cb) {
    const int c0 = cb * 32;
    __syncthreads();
#pragma unroll
    for (int k = 0; k < 8; ++k) {
      const int e = tid + k * 256;
      const int o = e >> 3, g = e & 7;
      const float4 wv = *(const float4*)&wp[(size_t)o * 256 + c0 + g * 4];
      wpT[g * 4 + 0][o] = f2b(wv.x);
      wpT[g * 4 + 1][o] = f2b(wv.y);
      wpT[g * 4 + 2][o] = f2b(wv.z);
      wpT[g * 4 + 3][o] = f2b(wv.w);
    }
    __syncthreads();
    for (int cc = 0; cc < 32; ++cc) {
      const uint4 bv = *(const uint4*)&bn[c0 + cc][pg * 8];
      float bf[8];
      bf[0] = b2f_lo(bv.x); bf[1] = b2f_hi(bv.x); bf[2] = b2f_lo(bv.y); bf[3] = b2f_hi(bv.y);
      bf[4] = b2f_lo(bv.z); bf[5] = b2f_hi(bv.z); bf[6] = b2f_lo(bv.w); bf[7] = b2f_hi(bv.w);
      const uint4 wv = *(const uint4*)&wpT[cc][og * 8];
      float wf[8];
      wf[0] = b2f_lo(wv.x); wf[1] = b2f_hi(wv.x); wf[2] = b2f_lo(wv.y); wf[3] = b2f_hi(wv.y);
      wf[4] = b2f_lo(wv.z); wf[5] = b2f_hi(wv.z); wf[6] = b2f_lo(wv.w); wf[7] = b2f_hi(wv.w);
#pragma unroll
      for (int a = 0; a < 8; ++a)
#pragma unroll
        for (int s = 0; s < 8; ++s) acc[a][s] += wf[a] * bf[s];
    }
  }
#pragma unroll
  for (int a = 0; a < 8; ++a) {
    const int o = og * 8 + a;
    float* op = out + (((size_t)(b * C_ + o)) * H_ + h) * W_ + w0 + pg * 8;
    float4 v0; v0.x = acc[a][0]; v0.y = acc[a][1]; v0.z = acc[a][2]; v0.w = acc[a][3];
    float4 v1; v1.x = acc[a][4]; v1.y = acc[a][5]; v1.z = acc[a][6]; v1.w = acc[a][7];
    *(float4*)op = v0;
    *(float4*)(op + 4) = v1;
  }
}

// ---------------------------------------------------------------------------
extern "C" void kernel_launch(void* const* d_in, const int* in_sizes, int n_in,
                              void* d_out, int out_size, void* d_ws, size_t ws_size,
                              hipStream_t stream)
{
  const float* x     = (const float*)d_in[0];
  const float* wqkv  = (const float*)d_in[1];
  const float* rel   = (const float*)d_in[2];
  const float* wax   = (const float*)d_in[3];
  const float* bax   = (const float*)d_in[4];
  const float* way   = (const float*)d_in[5];
  const float* bay   = (const float*)d_in[6];
  const float* wdw   = (const float*)d_in[7];
  const float* gam   = (const float*)d_in[8];
  const float* bet   = (const float*)d_in[9];
  const float* mea   = (const float*)d_in[10];
  const float* var   = (const float*)d_in[11];
  const float* wproj = (const float*)d_in[12];
  float* out = (float*)d_out;

  const size_t N = (size_t)B_ * C_ * H_ * W_;
  u16* oNHWC  = (u16*)d_out;        // bf16 o, NHWC (first half of f32 out)
  u16* out1b  = (u16*)d_out + N;    // bf16 out1, NCHW (second half)
  u16* wtbuf  = (u16*)d_ws;         // bf16 WT [2][8][256][256] (2 MB) + wqkv bf16 (384 KB)
  u16* bnbuf  = (u16*)d_ws;         // bf16 bn, NCHW (reuses WT region after K2)

  hipLaunchKernelGGL(k_wt,     dim3(256),  dim3(256), 0, stream, wax, way, wqkv, wtbuf);
  hipLaunchKernelGGL(k_attn,   dim3(2048), dim3(256), 0, stream, x, wtbuf + 1048576, rel, oNHWC);
  hipLaunchKernelGGL(k_conv2m, dim3(2048), dim3(256), 0, stream, oNHWC, wtbuf, bax, bay, out1b);
  hipLaunchKernelGGL(k_dwbn,   dim3(8192), dim3(256), 0, stream, out1b, wdw, gam, bet, mea, var, bnbuf);
  hipLaunchKernelGGL(k_proj,   dim3(2048), dim3(256), 0, stream, bnbuf, wproj, out);
}

// Round 2
// 1246.239 us; speedup vs baseline: 1.8609x; 1.4602x over previous
//
#include <hip/hip_runtime.h>
#include <stdint.h>

// GlobalAttention fused pipeline, MI355X gfx950.
// Round 6: k_attn phase-3 rebuilt barrier-free per-wave (4 heads/wave) with
// MFMA QK^T (swapped, in-lane softmax) and MFMA PV; k_proj moved to MFMA.
//   K0: wx,wy -> WT bf16; wqkv -> w8 bf16 [768][256]; rel -> biasT[16][64][64] f32
//   K1: x -> xb LDS once; MFMA qkv GEMM (head-remapped); per-wave attention
//   K2: o,WT -> out1 NCHW bf16 [MFMA]  (unchanged)
//   K3: out1 -> bn NCHW bf16 @ d_ws    (unchanged)
//   K4: bn -> d_out f32 final          [MFMA, new]

#define B_ 2
#define C_ 256
#define H_ 256
#define W_ 256
#define HW_ 65536

typedef unsigned short u16;
typedef unsigned int u32;
typedef short bf16x8 __attribute__((ext_vector_type(8)));
typedef float f32x4 __attribute__((ext_vector_type(4)));
typedef float f32x16 __attribute__((ext_vector_type(16)));

__device__ __forceinline__ float b2f(u16 h) {
  union { u32 u; float f; } x; x.u = ((u32)h) << 16; return x.f;
}
__device__ __forceinline__ float b2f_lo(u32 u) {
  union { u32 v; float f; } x; x.v = u << 16; return x.f;
}
__device__ __forceinline__ float b2f_hi(u32 u) {
  union { u32 v; float f; } x; x.v = u & 0xffff0000u; return x.f;
}
__device__ __forceinline__ u16 f2b(float f) {  // RNE
  union { float f; u32 u; } x; x.f = f;
  return (u16)((x.u + 0x7fffu + ((x.u >> 16) & 1u)) >> 16);
}
__device__ __forceinline__ u32 pack2(float a, float b) {
  return (u32)f2b(a) | ((u32)f2b(b) << 16);
}
// fast round-half-up bf16 pack: 3 ops via v_perm
__device__ __forceinline__ u32 pack2rn(float a, float b) {
  u32 ua = __float_as_uint(a) + 0x8000u;
  u32 ub = __float_as_uint(b) + 0x8000u;
  return __builtin_amdgcn_perm(ub, ua, 0x07060302u);
}
__device__ __forceinline__ u16 f2brn(float f) {
  return (u16)((__float_as_uint(f) + 0x8000u) >> 16);
}

// ---------------------------------------------------------------------------
// K0: WT bf16 [conv][t][o][c]; wqkv -> w8 bf16 [768][256];
//     rel -> biasT[head][j][i] f32 (16*64*64)
// ---------------------------------------------------------------------------
__global__ __launch_bounds__(256) void k_wt(
    const float* __restrict__ wx, const float* __restrict__ wy,
    const float* __restrict__ wqkv, const float* __restrict__ rel,
    u16* __restrict__ wt, float* __restrict__ biasT)
{
  const int o = blockIdx.x, c = threadIdx.x;
  const float* px = wx + ((size_t)o * 256 + c) * 8;
  const float* py = wy + ((size_t)o * 256 + c) * 8;
#pragma unroll
  for (int t = 0; t < 8; ++t) {
    wt[(size_t)t * 65536 + o * 256 + c]          = f2b(px[t]);
    wt[524288 + (size_t)t * 65536 + o * 256 + c] = f2b(py[t]);
  }
  u16* w8 = wt + 1048576;
#pragma unroll
  for (int t = 0; t < 3; ++t) {
    const int row = o + t * 256;
    w8[(size_t)row * 256 + c] = f2b(wqkv[(size_t)row * 256 + c]);
  }
  // biasT[h][j][i] = rel[ridx(i,j)*16+h]
  const int flat = o * 256 + c;
  const int h = flat >> 12, j = (flat >> 6) & 63, i = flat & 63;
  const int iy = i >> 3, ix = i & 7, jy = j >> 3, jx = j & 7;
  const int ridx = (iy - jy + 7) * 15 + (ix - jx + 7);
  biasT[flat] = rel[ridx * 16 + h];
}

// ---------------------------------------------------------------------------
// K1: qkv (MFMA) + windowed attention (per-wave, barrier-free phase 3).
// Wave w owns heads 4w..4w+3 (q/k/v channels 64w..64w+63).
// ---------------------------------------------------------------------------
__global__ __launch_bounds__(256) void k_attn(
    const float* __restrict__ x, const u16* __restrict__ w8,
    const float* __restrict__ biasT, u16* __restrict__ o_img)
{
  __shared__ __align__(16) union {
    u16 xb[64][264];   // phase 1-2: x window [px][c] bf16
    u16 P[4][4096];    // phase 3: per-wave P tile [i][j], XOR-swizzled
  } U;
  __shared__ __align__(16) u16 q_s[64][264];   // [px][ch], q pre-scaled 0.25
  __shared__ __align__(16) u16 k_s[64][264];   // [px][ch]
  __shared__ __align__(16) u16 v_sT[256][72];  // [ch][px]

  const int tid = threadIdx.x;
  const int nb  = blockIdx.x;
  const int b   = nb >> 10;
  const int hh  = (nb >> 5) & 31;
  const int ww  = nb & 31;
  const int h0  = hh << 3, w0 = ww << 3;

  // ---- phase 1: stage x window -> xb [px][c] bf16 ----
  {
    const int c2 = tid & 127;
    const int half = tid >> 7;
    const float* p0 = x + (((size_t)(b * C_ + 2 * c2)) * H_ + (h0 + half * 4)) * W_ + w0;
    const float* p1 = p0 + (size_t)H_ * W_;
#pragma unroll
    for (int r = 0; r < 4; ++r) {
      const float4 a0 = *(const float4*)(p0 + r * W_);
      const float4 a1 = *(const float4*)(p0 + r * W_ + 4);
      const float4 b0 = *(const float4*)(p1 + r * W_);
      const float4 b1 = *(const float4*)(p1 + r * W_ + 4);
      const float fa[8] = {a0.x, a0.y, a0.z, a0.w, a1.x, a1.y, a1.z, a1.w};
      const float fb[8] = {b0.x, b0.y, b0.z, b0.w, b1.x, b1.y, b1.z, b1.w};
      const int px0 = (half * 4 + r) * 8;
#pragma unroll
      for (int cc = 0; cc < 8; ++cc)
        *(u32*)&U.xb[px0 + cc][2 * c2] = pack2rn(fa[cc], fb[cc]);
    }
  }
  __syncthreads();

  // ---- phase 2: MFMA GEMM, wave w computes rows for its own heads ----
  const int lane = tid & 63, wid = tid >> 6;
  const int n = lane & 31, h5 = lane >> 5;

  f32x16 acc[6][2];
#pragma unroll
  for (int mt = 0; mt < 6; ++mt)
#pragma unroll
    for (int nt = 0; nt < 2; ++nt)
#pragma unroll
      for (int i = 0; i < 16; ++i) acc[mt][nt][i] = 0.f;

#pragma unroll 2
  for (int kb = 0; kb < 16; ++kb) {
    const int k0 = kb * 16;
    bf16x8 bfr[2];
#pragma unroll
    for (int nt = 0; nt < 2; ++nt) {
      union { uint4 u; bf16x8 v; } T;
      T.u = *(const uint4*)&U.xb[nt * 32 + n][k0 + h5 * 8];
      bfr[nt] = T.v;
    }
#pragma unroll
    for (int mt = 0; mt < 6; ++mt) {
      // q rows: wid*64.., k rows: 256+wid*64.., v rows: 512+wid*64..
      const int row = (mt >> 1) * 256 + wid * 64 + (mt & 1) * 32 + n;
      union { uint4 u; bf16x8 v; } A;
      A.u = *(const uint4*)(w8 + (size_t)row * 256 + k0 + h5 * 8);
      acc[mt][0] = __builtin_amdgcn_mfma_f32_32x32x16_bf16(A.v, bfr[0], acc[mt][0], 0, 0, 0);
      acc[mt][1] = __builtin_amdgcn_mfma_f32_32x32x16_bf16(A.v, bfr[1], acc[mt][1], 0, 0, 0);
    }
  }

  // ---- phase 2.5: scatter q,k -> [px][ch] (u32 pairs); v -> [ch][px] ----
  const int chb0 = wid * 64 + 4 * h5;
#pragma unroll
  for (int mt = 0; mt < 4; ++mt) {
    u16 (*dst)[264] = (mt < 2) ? q_s : k_s;
    const float qs = (mt < 2) ? 0.25f : 1.0f;
    const int chb = chb0 + (mt & 1) * 32;
#pragma unroll
    for (int nt = 0; nt < 2; ++nt) {
      const int px = nt * 32 + n;
#pragma unroll
      for (int m = 0; m < 8; ++m) {
        const int ch = chb + ((2 * m) & 3) + 8 * (m >> 1);
        *(u32*)&dst[px][ch] =
            pack2rn(acc[mt][nt][2 * m] * qs, acc[mt][nt][2 * m + 1] * qs);
      }
    }
  }
#pragma unroll
  for (int mt = 4; mt < 6; ++mt) {
    const int chb = chb0 + (mt & 1) * 32;
#pragma unroll
    for (int nt = 0; nt < 2; ++nt) {
      const int px = nt * 32 + n;
#pragma unroll
      for (int r = 0; r < 16; ++r) {
        const int ch = chb + (r & 3) + 8 * (r >> 2);
        v_sT[ch][px] = f2brn(acc[mt][nt][r]);
      }
    }
  }
  __syncthreads();  // protect xb->P union across all waves

  // ---- phase 3: per-wave attention, 4 heads, no barriers ----
  u16* Pw = U.P[wid];
  const int il = lane & 15, jg = lane >> 4;

  for (int hl = 0; hl < 4; ++hl) {
    const int head = wid * 4 + hl;
    const int hb = head * 16;

    // QK^T swapped: S^T[j][i] = K[j][d] . Q^T[d][i]   (scale folded into q)
    bf16x8 ak[2], bq[2];
#pragma unroll
    for (int jt = 0; jt < 2; ++jt) {
      union { uint4 u; bf16x8 v; } T;
      T.u = *(const uint4*)&k_s[jt * 32 + n][hb + h5 * 8];
      ak[jt] = T.v;
    }
#pragma unroll
    for (int it = 0; it < 2; ++it) {
      union { uint4 u; bf16x8 v; } T;
      T.u = *(const uint4*)&q_s[it * 32 + n][hb + h5 * 8];
      bq[it] = T.v;
    }
    f32x16 zro;
#pragma unroll
    for (int e = 0; e < 16; ++e) zro[e] = 0.f;
    f32x16 s[2][2];
#pragma unroll
    for (int jt = 0; jt < 2; ++jt)
#pragma unroll
      for (int it = 0; it < 2; ++it)
        s[jt][it] = __builtin_amdgcn_mfma_f32_32x32x16_bf16(ak[jt], bq[it], zro, 0, 0, 0);

    // + bias (biasT[head][j][i], coalesced over i = lanes)
    const float* bT = biasT + head * 4096;
#pragma unroll
    for (int jt = 0; jt < 2; ++jt)
#pragma unroll
      for (int it = 0; it < 2; ++it)
#pragma unroll
        for (int r = 0; r < 16; ++r) {
          const int j = jt * 32 + (r & 3) + 8 * (r >> 2) + 4 * h5;
          s[jt][it][r] += bT[j * 64 + it * 32 + n];
        }

    // in-lane softmax per i-row (lane pair n, n+32 holds the two j-halves)
#pragma unroll
    for (int it = 0; it < 2; ++it) {
      const int i = it * 32 + n;
      float mx = s[0][it][0];
#pragma unroll
      for (int jt = 0; jt < 2; ++jt)
#pragma unroll
        for (int r = 0; r < 16; ++r) mx = fmaxf(mx, s[jt][it][r]);
      mx = fmaxf(mx, __shfl_xor(mx, 32));
      float sum = 0.f;
#pragma unroll
      for (int jt = 0; jt < 2; ++jt)
#pragma unroll
        for (int r = 0; r < 16; ++r) {
          const float p = __expf(s[jt][it][r] - mx);
          s[jt][it][r] = p;
          sum += p;
        }
      sum += __shfl_xor(sum, 32);
      const float rs = 1.0f / sum;
      const u32 rowoff = (u32)(i * 128);
      const u32 swz = (u32)((i & 7) << 4);
#pragma unroll
      for (int jt = 0; jt < 2; ++jt)
#pragma unroll
        for (int m = 0; m < 8; ++m) {
          const int j = jt * 32 + ((2 * m) & 3) + 8 * (m >> 1) + 4 * h5;
          const u32 off = (rowoff + (u32)(j * 2)) ^ swz;
          *(u32*)((char*)Pw + off) =
              pack2rn(s[jt][it][2 * m] * rs, s[jt][it][2 * m + 1] * rs);
        }
    }

    // PV: O[64i][16d] = P[64x64] . V[64x16]  (16x16x32, N = d = 16 exactly)
    bf16x8 bv[2];
#pragma unroll
    for (int ks = 0; ks < 2; ++ks) {
      union { uint4 u; bf16x8 v; } T;
      T.u = *(const uint4*)&v_sT[hb + il][ks * 32 + jg * 8];
      bv[ks] = T.v;
    }
#pragma unroll
    for (int it2 = 0; it2 < 4; ++it2) {
      f32x4 pv = {0.f, 0.f, 0.f, 0.f};
#pragma unroll
      for (int ks = 0; ks < 2; ++ks) {
        const int i = it2 * 16 + il;
        const u32 off =
            ((u32)(i * 128 + ks * 64 + jg * 16)) ^ ((u32)((i & 7) << 4));
        union { uint4 u; bf16x8 v; } A;
        A.u = *(const uint4*)((const char*)Pw + off);
        pv = __builtin_amdgcn_mfma_f32_16x16x32_bf16(A.v, bv[ks], pv, 0, 0, 0);
      }
#pragma unroll
      for (int rr = 0; rr < 4; ++rr) {
        const int i = it2 * 16 + jg * 4 + rr;
        const int iy = i >> 3, ix = i & 7;
        o_img[(((size_t)(b * H_ + h0 + iy)) * W_ + (w0 + ix)) * C_ + hb + il] =
            f2brn(pv[rr]);
      }
    }
  }
}

// ---------------------------------------------------------------------------
// K2 (MFMA): out1 = ox + oy + bx + by.  (unchanged)
// ---------------------------------------------------------------------------
__global__ __launch_bounds__(256) void k_conv2m(
    const u16* __restrict__ o_nhwc, const u16* __restrict__ wt,
    const float* __restrict__ bxg, const float* __restrict__ byg,
    u16* __restrict__ out1)
{
  __shared__ u16 tile[8 * 136 * 20];   // 43.5 KB
  __shared__ float bias_l[128];

  const int tid = threadIdx.x, nb = blockIdx.x;
  const int wh = nb & 1, oh = (nb >> 1) & 1, h = (nb >> 2) & 255, b = nb >> 10;
  const int ob = oh * 128, wb0 = wh * 128;
  const int lane = tid & 63, wid = tid >> 6;
  const int wo = (wid >> 1) * 64, wwv = (wid & 1) * 64;
  const int n = lane & 31, h5 = lane >> 5;

  if (tid < 128) bias_l[tid] = bxg[ob + tid] + byg[ob + tid];

  f32x16 acc[2][2];
#pragma unroll
  for (int mt = 0; mt < 2; ++mt)
#pragma unroll
    for (int nt = 0; nt < 2; ++nt)
#pragma unroll
      for (int i = 0; i < 16; ++i) acc[mt][nt][i] = 0.f;

  for (int cb = 0; cb < 16; ++cb) {
    const int c0 = cb * 16;
    __syncthreads();
    for (int e = tid; e < 1088; e += 256) {
      const int r = e / 136, wi = e - r * 136;
      const int hp = h - 3 + r;
      const int wp = wb0 + wi - 4;
      uint2 v0 = make_uint2(0, 0), v1 = v0, v2 = v0, v3 = v0;
      if (hp >= 0 && hp <= 256 && wp >= 0 && wp <= 256) {
        const int hr = (hp == 256) ? 254 : hp;
        const int wr = (wp == 256) ? 254 : wp;
        const u16* src = o_nhwc + (((size_t)(b * H_ + hr)) * W_ + wr) * C_ + c0;
        const uint4 A  = *(const uint4*)src;
        const uint4 Bv = *(const uint4*)(src + 8);
        v0 = make_uint2(A.x, A.y);  v1 = make_uint2(A.z, A.w);
        v2 = make_uint2(Bv.x, Bv.y); v3 = make_uint2(Bv.z, Bv.w);
      }
      u16* d = &tile[(r * 136 + wi) * 20];
      *(uint2*)(d)      = v0;
      *(uint2*)(d + 4)  = v1;
      *(uint2*)(d + 8)  = v2;
      *(uint2*)(d + 12) = v3;
    }
    __syncthreads();
#pragma unroll
    for (int cv = 0; cv < 2; ++cv) {
      const u16* wbase = wt + (size_t)cv * 524288;
#pragma unroll
      for (int t = 0; t < 8; ++t) {
        bf16x8 a[2], bb[2];
#pragma unroll
        for (int mt = 0; mt < 2; ++mt) {
          const int o = ob + wo + mt * 32 + n;
          union { uint4 u; bf16x8 v; } Uu;
          Uu.u = *(const uint4*)(wbase + ((size_t)(t * 256 + o)) * 256 + c0 + h5 * 8);
          a[mt] = Uu.v;
        }
#pragma unroll
        for (int nt = 0; nt < 2; ++nt) {
          const int rr = cv ? 3 : t;
          const int wi = wwv + nt * 32 + n + (cv ? (t + 1) : 4);
          const u16* p = &tile[(rr * 136 + wi) * 20 + h5 * 8];
          union { uint2 u[2]; bf16x8 v; } Uu;
          Uu.u[0] = *(const uint2*)p;
          Uu.u[1] = *(const uint2*)(p + 4);
          bb[nt] = Uu.v;
        }
        acc[0][0] = __builtin_amdgcn_mfma_f32_32x32x16_bf16(a[0], bb[0], acc[0][0], 0, 0, 0);
        acc[0][1] = __builtin_amdgcn_mfma_f32_32x32x16_bf16(a[0], bb[1], acc[0][1], 0, 0, 0);
        acc[1][0] = __builtin_amdgcn_mfma_f32_32x32x16_bf16(a[1], bb[0], acc[1][0], 0, 0, 0);
        acc[1][1] = __builtin_amdgcn_mfma_f32_32x32x16_bf16(a[1], bb[1], acc[1][1], 0, 0, 0);
      }
    }
  }
#pragma unroll
  for (int mt = 0; mt < 2; ++mt)
#pragma unroll
    for (int nt = 0; nt < 2; ++nt)
#pragma unroll
      for (int r = 0; r < 16; ++r) {
        const int om = wo + mt * 32 + (r & 3) + 8 * (r >> 2) + 4 * h5;
        const int o = ob + om;
        const int wg = wb0 + wwv + nt * 32 + n;
        const float v = acc[mt][nt][r] + bias_l[om];
        out1[(((size_t)(b * C_ + o)) * H_ + h) * W_ + wg] = f2b(v);
      }
}

// ---------------------------------------------------------------------------
// K3: depthwise 8x8 conv + BN (unchanged).
// ---------------------------------------------------------------------------
__global__ __launch_bounds__(256) void k_dwbn(
    const u16* __restrict__ out1, const float* __restrict__ wdw,
    const float* __restrict__ gam, const float* __restrict__ bet,
    const float* __restrict__ mea, const float* __restrict__ var,
    u16* __restrict__ bno)
{
  __shared__ u16 tile[23][264];
  const int tid = threadIdx.x, nb = blockIdx.x;
  const int c = nb & 255, ht = (nb >> 8) & 15, b = nb >> 12;
  const int h0 = ht * 16;

  for (int e = tid; e < 23 * 264; e += 256) {
    const int tr = e / 264, tc = e % 264;
    const int r = h0 - 3 + tr;
    const int cg = tc - 3;
    u16 v = 0;
    if (r >= 0 && r <= 256 && cg >= 0 && cg <= 256) {
      const int rr = (r == 256) ? 254 : r;
      const int cgm = (cg == 256) ? 254 : cg;
      v = out1[(((size_t)(b * C_ + c)) * H_ + rr) * W_ + cgm];
    }
    tile[tr][tc] = v;
  }
  float wk[64];
#pragma unroll
  for (int k2 = 0; k2 < 64; ++k2) wk[k2] = wdw[c * 64 + k2];
  const float scl = gam[c] / sqrtf(var[c] + 1e-5f);
  const float shf = bet[c] - mea[c] * scl;
  __syncthreads();

  const int wg = tid & 31, hg = tid >> 5;
  const int w0 = wg * 8;
#pragma unroll
  for (int k = 0; k < 2; ++k) {
    const int hl = hg * 2 + k;
    float a[8];
#pragma unroll
    for (int s = 0; s < 8; ++s) a[s] = 0.f;
#pragma unroll
    for (int i = 0; i < 8; ++i) {
      const uint4 va = *(const uint4*)&tile[hl + i][w0];
      const uint4 vb = *(const uint4*)&tile[hl + i][w0 + 8];
      float f[16];
      f[0] = b2f_lo(va.x);  f[1] = b2f_hi(va.x);  f[2] = b2f_lo(va.y);  f[3] = b2f_hi(va.y);
      f[4] = b2f_lo(va.z);  f[5] = b2f_hi(va.z);  f[6] = b2f_lo(va.w);  f[7] = b2f_hi(va.w);
      f[8] = b2f_lo(vb.x);  f[9] = b2f_hi(vb.x);  f[10] = b2f_lo(vb.y); f[11] = b2f_hi(vb.y);
      f[12] = b2f_lo(vb.z); f[13] = b2f_hi(vb.z); f[14] = b2f_lo(vb.w); f[15] = b2f_hi(vb.w);
#pragma unroll
      for (int j = 0; j < 8; ++j) {
        const float wv = wk[i * 8 + j];
#pragma unroll
        for (int s = 0; s < 8; ++s) a[s] += f[s + j] * wv;
      }
    }
    uint4 uv;
    uv.x = pack2(a[0] * scl + shf, a[1] * scl + shf);
    uv.y = pack2(a[2] * scl + shf, a[3] * scl + shf);
    uv.z = pack2(a[4] * scl + shf, a[5] * scl + shf);
    uv.w = pack2(a[6] * scl + shf, a[7] * scl + shf);
    *(uint4*)&bno[(((size_t)(b * C_ + c)) * H_ + h0 + hl) * W_ + w0] = uv;
  }
}

// ---------------------------------------------------------------------------
// K4 (MFMA): 1x1 projection. A = wproj (f32, packed in-flight), B = bn NCHW
// bf16 (coalesced ushort loads along px). No LDS, no barriers. Output f32.
// ---------------------------------------------------------------------------
__global__ __launch_bounds__(256) void k_projm(
    const u16* __restrict__ bn, const float* __restrict__ wp, float* __restrict__ out)
{
  const int tid = threadIdx.x, nb = blockIdx.x;
  const int oh = nb & 1;
  const int pb = nb >> 1;            // 0..1023
  const int b  = pb >> 9;
  const int px0 = (pb & 511) << 7;   // 128-px slab (linear in NCHW plane)
  const int lane = tid & 63, wid = tid >> 6;
  const int wo = (wid >> 1) * 64, wpx = (wid & 1) * 64;
  const int n = lane & 31, h5 = lane >> 5;
  const int ob = oh * 128;
  const int pxl = px0 + wpx + n;

  f32x16 acc[2][2];
#pragma unroll
  for (int mt = 0; mt < 2; ++mt)
#pragma unroll
    for (int nt = 0; nt < 2; ++nt)
#pragma unroll
      for (int i = 0; i < 16; ++i) acc[mt][nt][i] = 0.f;

  const u16* bnb = bn + (size_t)b * C_ * HW_;
#pragma unroll 2
  for (int cb = 0; cb < 16; ++cb) {
    const int c0 = cb * 16;
    bf16x8 a[2];
#pragma unroll
    for (int mt = 0; mt < 2; ++mt) {
      const int row = ob + wo + mt * 32 + n;
      const float4 w0v = *(const float4*)&wp[(size_t)row * 256 + c0 + h5 * 8];
      const float4 w1v = *(const float4*)&wp[(size_t)row * 256 + c0 + h5 * 8 + 4];
      union { u32 u[4]; bf16x8 v; } T;
      T.u[0] = pack2rn(w0v.x, w0v.y);
      T.u[1] = pack2rn(w0v.z, w0v.w);
      T.u[2] = pack2rn(w1v.x, w1v.y);
      T.u[3] = pack2rn(w1v.z, w1v.w);
      a[mt] = T.v;
    }
    bf16x8 bb[2];
#pragma unroll
    for (int nt = 0; nt < 2; ++nt) {
      const u16* sp = bnb + (size_t)(c0 + h5 * 8) * HW_ + (pxl + nt * 32);
      const u32 e0 = sp[0 * HW_], e1 = sp[1 * HW_], e2 = sp[2 * HW_], e3 = sp[3 * HW_];
      const u32 e4 = sp[4 * HW_], e5 = sp[5 * HW_], e6 = sp[6 * HW_], e7 = sp[7 * HW_];
      union { u32 u[4]; bf16x8 v; } T;
      T.u[0] = e0 | (e1 << 16);
      T.u[1] = e2 | (e3 << 16);
      T.u[2] = e4 | (e5 << 16);
      T.u[3] = e6 | (e7 << 16);
      bb[nt] = T.v;
    }
    acc[0][0] = __builtin_amdgcn_mfma_f32_32x32x16_bf16(a[0], bb[0], acc[0][0], 0, 0, 0);
    acc[0][1] = __builtin_amdgcn_mfma_f32_32x32x16_bf16(a[0], bb[1], acc[0][1], 0, 0, 0);
    acc[1][0] = __builtin_amdgcn_mfma_f32_32x32x16_bf16(a[1], bb[0], acc[1][0], 0, 0, 0);
    acc[1][1] = __builtin_amdgcn_mfma_f32_32x32x16_bf16(a[1], bb[1], acc[1][1], 0, 0, 0);
  }
#pragma unroll
  for (int mt = 0; mt < 2; ++mt)
#pragma unroll
    for (int nt = 0; nt < 2; ++nt)
#pragma unroll
      for (int r = 0; r < 16; ++r) {
        const int o = ob + wo + mt * 32 + (r & 3) + 8 * (r >> 2) + 4 * h5;
        out[((size_t)(b * C_ + o)) * HW_ + (pxl + nt * 32)] = acc[mt][nt][r];
      }
}

// ---------------------------------------------------------------------------
extern "C" void kernel_launch(void* const* d_in, const int* in_sizes, int n_in,
                              void* d_out, int out_size, void* d_ws, size_t ws_size,
                              hipStream_t stream)
{
  const float* x     = (const float*)d_in[0];
  const float* wqkv  = (const float*)d_in[1];
  const float* rel   = (const float*)d_in[2];
  const float* wax   = (const float*)d_in[3];
  const float* bax   = (const float*)d_in[4];
  const float* way   = (const float*)d_in[5];
  const float* bay   = (const float*)d_in[6];
  const float* wdw   = (const float*)d_in[7];
  const float* gam   = (const float*)d_in[8];
  const float* bet   = (const float*)d_in[9];
  const float* mea   = (const float*)d_in[10];
  const float* var   = (const float*)d_in[11];
  const float* wproj = (const float*)d_in[12];
  float* out = (float*)d_out;

  const size_t N = (size_t)B_ * C_ * H_ * W_;
  u16* oNHWC  = (u16*)d_out;        // bf16 o, NHWC (first half of f32 out)
  u16* out1b  = (u16*)d_out + N;    // bf16 out1, NCHW (second half)
  u16* wtbuf  = (u16*)d_ws;         // WT 2MB + w8 384KB (bf16)
  float* biasT = (float*)((char*)d_ws + 2490368);  // 256KB, after WT+w8
  u16* bnbuf  = (u16*)d_ws;         // bn NCHW bf16 (reuses region after K2)

  hipLaunchKernelGGL(k_wt,     dim3(256),  dim3(256), 0, stream, wax, way, wqkv, rel, wtbuf, biasT);
  hipLaunchKernelGGL(k_attn,   dim3(2048), dim3(256), 0, stream, x, wtbuf + 1048576, biasT, oNHWC);
  hipLaunchKernelGGL(k_conv2m, dim3(2048), dim3(256), 0, stream, oNHWC, wtbuf, bax, bay, out1b);
  hipLaunchKernelGGL(k_dwbn,   dim3(8192), dim3(256), 0, stream, out1b, wdw, gam, bet, mea, var, bnbuf);
  hipLaunchKernelGGL(k_projm,  dim3(2048), dim3(256), 0, stream, bnbuf, wproj, out);
}

// Round 3
// 1222.505 us; speedup vs baseline: 1.8970x; 1.0194x over previous
//
#include <hip/hip_runtime.h>
#include <stdint.h>

// GlobalAttention fused pipeline, MI355X gfx950.
// Round 7: k_conv2m restructured -- 2 output rows per block, 512 threads
// (8 waves of 64x64), 9-row halo staged per 16-c chunk. Halves staging work
// per MFMA and doubles occupancy (23% -> ~50%).
//   K0: wx,wy -> WT bf16; wqkv -> w8 bf16 [768][256]; rel -> biasT[16][64][64] f32
//   K1: x -> xb LDS once; MFMA qkv GEMM (head-remapped); per-wave attention
//   K2: o,WT -> out1 NCHW bf16 [MFMA, 2 rows/block]
//   K3: out1 -> bn NCHW bf16 @ d_ws
//   K4: bn -> d_out f32 final [MFMA]

#define B_ 2
#define C_ 256
#define H_ 256
#define W_ 256
#define HW_ 65536

typedef unsigned short u16;
typedef unsigned int u32;
typedef short bf16x8 __attribute__((ext_vector_type(8)));
typedef float f32x4 __attribute__((ext_vector_type(4)));
typedef float f32x16 __attribute__((ext_vector_type(16)));

__device__ __forceinline__ float b2f(u16 h) {
  union { u32 u; float f; } x; x.u = ((u32)h) << 16; return x.f;
}
__device__ __forceinline__ float b2f_lo(u32 u) {
  union { u32 v; float f; } x; x.v = u << 16; return x.f;
}
__device__ __forceinline__ float b2f_hi(u32 u) {
  union { u32 v; float f; } x; x.v = u & 0xffff0000u; return x.f;
}
__device__ __forceinline__ u16 f2b(float f) {  // RNE
  union { float f; u32 u; } x; x.f = f;
  return (u16)((x.u + 0x7fffu + ((x.u >> 16) & 1u)) >> 16);
}
__device__ __forceinline__ u32 pack2(float a, float b) {
  return (u32)f2b(a) | ((u32)f2b(b) << 16);
}
// fast round-half-up bf16 pack: 3 ops via v_perm
__device__ __forceinline__ u32 pack2rn(float a, float b) {
  u32 ua = __float_as_uint(a) + 0x8000u;
  u32 ub = __float_as_uint(b) + 0x8000u;
  return __builtin_amdgcn_perm(ub, ua, 0x07060302u);
}
__device__ __forceinline__ u16 f2brn(float f) {
  return (u16)((__float_as_uint(f) + 0x8000u) >> 16);
}

// ---------------------------------------------------------------------------
// K0: WT bf16 [conv][t][o][c]; wqkv -> w8 bf16 [768][256];
//     rel -> biasT[head][j][i] f32 (16*64*64)
// ---------------------------------------------------------------------------
__global__ __launch_bounds__(256) void k_wt(
    const float* __restrict__ wx, const float* __restrict__ wy,
    const float* __restrict__ wqkv, const float* __restrict__ rel,
    u16* __restrict__ wt, float* __restrict__ biasT)
{
  const int o = blockIdx.x, c = threadIdx.x;
  const float* px = wx + ((size_t)o * 256 + c) * 8;
  const float* py = wy + ((size_t)o * 256 + c) * 8;
#pragma unroll
  for (int t = 0; t < 8; ++t) {
    wt[(size_t)t * 65536 + o * 256 + c]          = f2b(px[t]);
    wt[524288 + (size_t)t * 65536 + o * 256 + c] = f2b(py[t]);
  }
  u16* w8 = wt + 1048576;
#pragma unroll
  for (int t = 0; t < 3; ++t) {
    const int row = o + t * 256;
    w8[(size_t)row * 256 + c] = f2b(wqkv[(size_t)row * 256 + c]);
  }
  // biasT[h][j][i] = rel[ridx(i,j)*16+h]
  const int flat = o * 256 + c;
  const int h = flat >> 12, j = (flat >> 6) & 63, i = flat & 63;
  const int iy = i >> 3, ix = i & 7, jy = j >> 3, jx = j & 7;
  const int ridx = (iy - jy + 7) * 15 + (ix - jx + 7);
  biasT[flat] = rel[ridx * 16 + h];
}

// ---------------------------------------------------------------------------
// K1: qkv (MFMA) + windowed attention (per-wave, barrier-free phase 3).
// Wave w owns heads 4w..4w+3 (q/k/v channels 64w..64w+63).
// ---------------------------------------------------------------------------
__global__ __launch_bounds__(256) void k_attn(
    const float* __restrict__ x, const u16* __restrict__ w8,
    const float* __restrict__ biasT, u16* __restrict__ o_img)
{
  __shared__ __align__(16) union {
    u16 xb[64][264];   // phase 1-2: x window [px][c] bf16
    u16 P[4][4096];    // phase 3: per-wave P tile [i][j], XOR-swizzled
  } U;
  __shared__ __align__(16) u16 q_s[64][264];   // [px][ch], q pre-scaled 0.25
  __shared__ __align__(16) u16 k_s[64][264];   // [px][ch]
  __shared__ __align__(16) u16 v_sT[256][72];  // [ch][px]

  const int tid = threadIdx.x;
  const int nb  = blockIdx.x;
  const int b   = nb >> 10;
  const int hh  = (nb >> 5) & 31;
  const int ww  = nb & 31;
  const int h0  = hh << 3, w0 = ww << 3;

  // ---- phase 1: stage x window -> xb [px][c] bf16 ----
  {
    const int c2 = tid & 127;
    const int half = tid >> 7;
    const float* p0 = x + (((size_t)(b * C_ + 2 * c2)) * H_ + (h0 + half * 4)) * W_ + w0;
    const float* p1 = p0 + (size_t)H_ * W_;
#pragma unroll
    for (int r = 0; r < 4; ++r) {
      const float4 a0 = *(const float4*)(p0 + r * W_);
      const float4 a1 = *(const float4*)(p0 + r * W_ + 4);
      const float4 b0 = *(const float4*)(p1 + r * W_);
      const float4 b1 = *(const float4*)(p1 + r * W_ + 4);
      const float fa[8] = {a0.x, a0.y, a0.z, a0.w, a1.x, a1.y, a1.z, a1.w};
      const float fb[8] = {b0.x, b0.y, b0.z, b0.w, b1.x, b1.y, b1.z, b1.w};
      const int px0 = (half * 4 + r) * 8;
#pragma unroll
      for (int cc = 0; cc < 8; ++cc)
        *(u32*)&U.xb[px0 + cc][2 * c2] = pack2rn(fa[cc], fb[cc]);
    }
  }
  __syncthreads();

  // ---- phase 2: MFMA GEMM, wave w computes rows for its own heads ----
  const int lane = tid & 63, wid = tid >> 6;
  const int n = lane & 31, h5 = lane >> 5;

  f32x16 acc[6][2];
#pragma unroll
  for (int mt = 0; mt < 6; ++mt)
#pragma unroll
    for (int nt = 0; nt < 2; ++nt)
#pragma unroll
      for (int i = 0; i < 16; ++i) acc[mt][nt][i] = 0.f;

#pragma unroll 2
  for (int kb = 0; kb < 16; ++kb) {
    const int k0 = kb * 16;
    bf16x8 bfr[2];
#pragma unroll
    for (int nt = 0; nt < 2; ++nt) {
      union { uint4 u; bf16x8 v; } T;
      T.u = *(const uint4*)&U.xb[nt * 32 + n][k0 + h5 * 8];
      bfr[nt] = T.v;
    }
#pragma unroll
    for (int mt = 0; mt < 6; ++mt) {
      // q rows: wid*64.., k rows: 256+wid*64.., v rows: 512+wid*64..
      const int row = (mt >> 1) * 256 + wid * 64 + (mt & 1) * 32 + n;
      union { uint4 u; bf16x8 v; } A;
      A.u = *(const uint4*)(w8 + (size_t)row * 256 + k0 + h5 * 8);
      acc[mt][0] = __builtin_amdgcn_mfma_f32_32x32x16_bf16(A.v, bfr[0], acc[mt][0], 0, 0, 0);
      acc[mt][1] = __builtin_amdgcn_mfma_f32_32x32x16_bf16(A.v, bfr[1], acc[mt][1], 0, 0, 0);
    }
  }

  // ---- phase 2.5: scatter q,k -> [px][ch] (u32 pairs); v -> [ch][px] ----
  const int chb0 = wid * 64 + 4 * h5;
#pragma unroll
  for (int mt = 0; mt < 4; ++mt) {
    u16 (*dst)[264] = (mt < 2) ? q_s : k_s;
    const float qs = (mt < 2) ? 0.25f : 1.0f;
    const int chb = chb0 + (mt & 1) * 32;
#pragma unroll
    for (int nt = 0; nt < 2; ++nt) {
      const int px = nt * 32 + n;
#pragma unroll
      for (int m = 0; m < 8; ++m) {
        const int ch = chb + ((2 * m) & 3) + 8 * (m >> 1);
        *(u32*)&dst[px][ch] =
            pack2rn(acc[mt][nt][2 * m] * qs, acc[mt][nt][2 * m + 1] * qs);
      }
    }
  }
#pragma unroll
  for (int mt = 4; mt < 6; ++mt) {
    const int chb = chb0 + (mt & 1) * 32;
#pragma unroll
    for (int nt = 0; nt < 2; ++nt) {
      const int px = nt * 32 + n;
#pragma unroll
      for (int r = 0; r < 16; ++r) {
        const int ch = chb + (r & 3) + 8 * (r >> 2);
        v_sT[ch][px] = f2brn(acc[mt][nt][r]);
      }
    }
  }
  __syncthreads();  // protect xb->P union across all waves

  // ---- phase 3: per-wave attention, 4 heads, no barriers ----
  u16* Pw = U.P[wid];
  const int il = lane & 15, jg = lane >> 4;

  for (int hl = 0; hl < 4; ++hl) {
    const int head = wid * 4 + hl;
    const int hb = head * 16;

    // QK^T swapped: S^T[j][i] = K[j][d] . Q^T[d][i]   (scale folded into q)
    bf16x8 ak[2], bq[2];
#pragma unroll
    for (int jt = 0; jt < 2; ++jt) {
      union { uint4 u; bf16x8 v; } T;
      T.u = *(const uint4*)&k_s[jt * 32 + n][hb + h5 * 8];
      ak[jt] = T.v;
    }
#pragma unroll
    for (int it = 0; it < 2; ++it) {
      union { uint4 u; bf16x8 v; } T;
      T.u = *(const uint4*)&q_s[it * 32 + n][hb + h5 * 8];
      bq[it] = T.v;
    }
    f32x16 zro;
#pragma unroll
    for (int e = 0; e < 16; ++e) zro[e] = 0.f;
    f32x16 s[2][2];
#pragma unroll
    for (int jt = 0; jt < 2; ++jt)
#pragma unroll
      for (int it = 0; it < 2; ++it)
        s[jt][it] = __builtin_amdgcn_mfma_f32_32x32x16_bf16(ak[jt], bq[it], zro, 0, 0, 0);

    // + bias (biasT[head][j][i], coalesced over i = lanes)
    const float* bT = biasT + head * 4096;
#pragma unroll
    for (int jt = 0; jt < 2; ++jt)
#pragma unroll
      for (int it = 0; it < 2; ++it)
#pragma unroll
        for (int r = 0; r < 16; ++r) {
          const int j = jt * 32 + (r & 3) + 8 * (r >> 2) + 4 * h5;
          s[jt][it][r] += bT[j * 64 + it * 32 + n];
        }

    // in-lane softmax per i-row (lane pair n, n+32 holds the two j-halves)
#pragma unroll
    for (int it = 0; it < 2; ++it) {
      const int i = it * 32 + n;
      float mx = s[0][it][0];
#pragma unroll
      for (int jt = 0; jt < 2; ++jt)
#pragma unroll
        for (int r = 0; r < 16; ++r) mx = fmaxf(mx, s[jt][it][r]);
      mx = fmaxf(mx, __shfl_xor(mx, 32));
      float sum = 0.f;
#pragma unroll
      for (int jt = 0; jt < 2; ++jt)
#pragma unroll
        for (int r = 0; r < 16; ++r) {
          const float p = __expf(s[jt][it][r] - mx);
          s[jt][it][r] = p;
          sum += p;
        }
      sum += __shfl_xor(sum, 32);
      const float rs = 1.0f / sum;
      const u32 rowoff = (u32)(i * 128);
      const u32 swz = (u32)((i & 7) << 4);
#pragma unroll
      for (int jt = 0; jt < 2; ++jt)
#pragma unroll
        for (int m = 0; m < 8; ++m) {
          const int j = jt * 32 + ((2 * m) & 3) + 8 * (m >> 1) + 4 * h5;
          const u32 off = (rowoff + (u32)(j * 2)) ^ swz;
          *(u32*)((char*)Pw + off) =
              pack2rn(s[jt][it][2 * m] * rs, s[jt][it][2 * m + 1] * rs);
        }
    }

    // PV: O[64i][16d] = P[64x64] . V[64x16]  (16x16x32, N = d = 16 exactly)
    bf16x8 bv[2];
#pragma unroll
    for (int ks = 0; ks < 2; ++ks) {
      union { uint4 u; bf16x8 v; } T;
      T.u = *(const uint4*)&v_sT[hb + il][ks * 32 + jg * 8];
      bv[ks] = T.v;
    }
#pragma unroll
    for (int it2 = 0; it2 < 4; ++it2) {
      f32x4 pv = {0.f, 0.f, 0.f, 0.f};
#pragma unroll
      for (int ks = 0; ks < 2; ++ks) {
        const int i = it2 * 16 + il;
        const u32 off =
            ((u32)(i * 128 + ks * 64 + jg * 16)) ^ ((u32)((i & 7) << 4));
        union { uint4 u; bf16x8 v; } A;
        A.u = *(const uint4*)((const char*)Pw + off);
        pv = __builtin_amdgcn_mfma_f32_16x16x32_bf16(A.v, bv[ks], pv, 0, 0, 0);
      }
#pragma unroll
      for (int rr = 0; rr < 4; ++rr) {
        const int i = it2 * 16 + jg * 4 + rr;
        const int iy = i >> 3, ix = i & 7;
        o_img[(((size_t)(b * H_ + h0 + iy)) * W_ + (w0 + ix)) * C_ + hb + il] =
            f2brn(pv[rr]);
      }
    }
  }
}

// ---------------------------------------------------------------------------
// K2 (MFMA): out1 = ox + oy + bx + by.
// Round 7: 2 output rows per block, 512 threads / 8 waves of 64x64.
// Tile: 9 halo rows x 136 w x 16 c per chunk (stride pad 20).
// ---------------------------------------------------------------------------
__global__ __launch_bounds__(512) void k_conv2m(
    const u16* __restrict__ o_nhwc, const u16* __restrict__ wt,
    const float* __restrict__ bxg, const float* __restrict__ byg,
    u16* __restrict__ out1)
{
  __shared__ u16 tile[9 * 136 * 20];   // 47.8 KB
  __shared__ float bias_l[128];

  const int tid = threadIdx.x, nb = blockIdx.x;
  const int wh = nb & 1, oh = (nb >> 1) & 1, hg = (nb >> 2) & 127, b = nb >> 9;
  const int h0 = hg << 1;             // 2 output rows h0, h0+1
  const int ob = oh * 128, wb0 = wh * 128;
  const int lane = tid & 63, wid = tid >> 6;
  const int o64 = (wid & 1) * 64;     // wave M-tile
  const int w64 = ((wid >> 1) & 1) * 64;  // wave N (w) tile
  const int hl  = wid >> 2;           // wave output row (0/1)
  const int n = lane & 31, h5 = lane >> 5;

  if (tid < 128) bias_l[tid] = bxg[ob + tid] + byg[ob + tid];

  f32x16 acc[2][2];
#pragma unroll
  for (int mt = 0; mt < 2; ++mt)
#pragma unroll
    for (int nt = 0; nt < 2; ++nt)
#pragma unroll
      for (int i = 0; i < 16; ++i) acc[mt][nt][i] = 0.f;

  for (int cb = 0; cb < 16; ++cb) {
    const int c0 = cb * 16;
    __syncthreads();
    // ---- stage 9 rows x 136 w x 16 c (NHWC source: 32B contiguous) ----
    for (int e = tid; e < 1224; e += 512) {
      const int r = e / 136, wi = e - r * 136;
      const int hp = h0 - 3 + r;
      const int wp = wb0 + wi - 4;
      uint2 v0 = make_uint2(0, 0), v1 = v0, v2 = v0, v3 = v0;
      if (hp >= 0 && hp <= 256 && wp >= 0 && wp <= 256) {
        const int hr = (hp == 256) ? 254 : hp;
        const int wr = (wp == 256) ? 254 : wp;
        const u16* src = o_nhwc + (((size_t)(b * H_ + hr)) * W_ + wr) * C_ + c0;
        const uint4 A  = *(const uint4*)src;
        const uint4 Bv = *(const uint4*)(src + 8);
        v0 = make_uint2(A.x, A.y);  v1 = make_uint2(A.z, A.w);
        v2 = make_uint2(Bv.x, Bv.y); v3 = make_uint2(Bv.z, Bv.w);
      }
      u16* d = &tile[(r * 136 + wi) * 20];
      *(uint2*)(d)      = v0;
      *(uint2*)(d + 4)  = v1;
      *(uint2*)(d + 8)  = v2;
      *(uint2*)(d + 12) = v3;
    }
    __syncthreads();
    // ---- compute: 2 convs x 8 taps, K=16 channels each ----
#pragma unroll
    for (int cv = 0; cv < 2; ++cv) {
      const u16* wbase = wt + (size_t)cv * 524288;
#pragma unroll
      for (int t = 0; t < 8; ++t) {
        bf16x8 a[2], bb[2];
#pragma unroll
        for (int mt = 0; mt < 2; ++mt) {
          const int o = ob + o64 + mt * 32 + n;
          union { uint4 u; bf16x8 v; } Uu;
          Uu.u = *(const uint4*)(wbase + ((size_t)(t * 256 + o)) * 256 + c0 + h5 * 8);
          a[mt] = Uu.v;
        }
#pragma unroll
        for (int nt = 0; nt < 2; ++nt) {
          const int rr = cv ? (hl + 3) : (hl + t);
          const int wi = w64 + nt * 32 + n + (cv ? (t + 1) : 4);
          const u16* p = &tile[(rr * 136 + wi) * 20 + h5 * 8];
          union { uint2 u[2]; bf16x8 v; } Uu;
          Uu.u[0] = *(const uint2*)p;
          Uu.u[1] = *(const uint2*)(p + 4);
          bb[nt] = Uu.v;
        }
        acc[0][0] = __builtin_amdgcn_mfma_f32_32x32x16_bf16(a[0], bb[0], acc[0][0], 0, 0, 0);
        acc[0][1] = __builtin_amdgcn_mfma_f32_32x32x16_bf16(a[0], bb[1], acc[0][1], 0, 0, 0);
        acc[1][0] = __builtin_amdgcn_mfma_f32_32x32x16_bf16(a[1], bb[0], acc[1][0], 0, 0, 0);
        acc[1][1] = __builtin_amdgcn_mfma_f32_32x32x16_bf16(a[1], bb[1], acc[1][1], 0, 0, 0);
      }
    }
  }
  // ---- epilogue: +bias, bf16, NCHW ----
#pragma unroll
  for (int mt = 0; mt < 2; ++mt)
#pragma unroll
    for (int nt = 0; nt < 2; ++nt)
#pragma unroll
      for (int r = 0; r < 16; ++r) {
        const int om = o64 + mt * 32 + (r & 3) + 8 * (r >> 2) + 4 * h5;
        const int o = ob + om;
        const int wg = wb0 + w64 + nt * 32 + n;
        const float v = acc[mt][nt][r] + bias_l[om];
        out1[(((size_t)(b * C_ + o)) * H_ + (h0 + hl)) * W_ + wg] = f2b(v);
      }
}

// ---------------------------------------------------------------------------
// K3: depthwise 8x8 conv + BN (unchanged).
// ---------------------------------------------------------------------------
__global__ __launch_bounds__(256) void k_dwbn(
    const u16* __restrict__ out1, const float* __restrict__ wdw,
    const float* __restrict__ gam, const float* __restrict__ bet,
    const float* __restrict__ mea, const float* __restrict__ var,
    u16* __restrict__ bno)
{
  __shared__ u16 tile[23][264];
  const int tid = threadIdx.x, nb = blockIdx.x;
  const int c = nb & 255, ht = (nb >> 8) & 15, b = nb >> 12;
  const int h0 = ht * 16;

  for (int e = tid; e < 23 * 264; e += 256) {
    const int tr = e / 264, tc = e % 264;
    const int r = h0 - 3 + tr;
    const int cg = tc - 3;
    u16 v = 0;
    if (r >= 0 && r <= 256 && cg >= 0 && cg <= 256) {
      const int rr = (r == 256) ? 254 : r;
      const int cgm = (cg == 256) ? 254 : cg;
      v = out1[(((size_t)(b * C_ + c)) * H_ + rr) * W_ + cgm];
    }
    tile[tr][tc] = v;
  }
  float wk[64];
#pragma unroll
  for (int k2 = 0; k2 < 64; ++k2) wk[k2] = wdw[c * 64 + k2];
  const float scl = gam[c] / sqrtf(var[c] + 1e-5f);
  const float shf = bet[c] - mea[c] * scl;
  __syncthreads();

  const int wg = tid & 31, hg = tid >> 5;
  const int w0 = wg * 8;
#pragma unroll
  for (int k = 0; k < 2; ++k) {
    const int hl = hg * 2 + k;
    float a[8];
#pragma unroll
    for (int s = 0; s < 8; ++s) a[s] = 0.f;
#pragma unroll
    for (int i = 0; i < 8; ++i) {
      const uint4 va = *(const uint4*)&tile[hl + i][w0];
      const uint4 vb = *(const uint4*)&tile[hl + i][w0 + 8];
      float f[16];
      f[0] = b2f_lo(va.x);  f[1] = b2f_hi(va.x);  f[2] = b2f_lo(va.y);  f[3] = b2f_hi(va.y);
      f[4] = b2f_lo(va.z);  f[5] = b2f_hi(va.z);  f[6] = b2f_lo(va.w);  f[7] = b2f_hi(va.w);
      f[8] = b2f_lo(vb.x);  f[9] = b2f_hi(vb.x);  f[10] = b2f_lo(vb.y); f[11] = b2f_hi(vb.y);
      f[12] = b2f_lo(vb.z); f[13] = b2f_hi(vb.z); f[14] = b2f_lo(vb.w); f[15] = b2f_hi(vb.w);
#pragma unroll
      for (int j = 0; j < 8; ++j) {
        const float wv = wk[i * 8 + j];
#pragma unroll
        for (int s = 0; s < 8; ++s) a[s] += f[s + j] * wv;
      }
    }
    uint4 uv;
    uv.x = pack2(a[0] * scl + shf, a[1] * scl + shf);
    uv.y = pack2(a[2] * scl + shf, a[3] * scl + shf);
    uv.z = pack2(a[4] * scl + shf, a[5] * scl + shf);
    uv.w = pack2(a[6] * scl + shf, a[7] * scl + shf);
    *(uint4*)&bno[(((size_t)(b * C_ + c)) * H_ + h0 + hl) * W_ + w0] = uv;
  }
}

// ---------------------------------------------------------------------------
// K4 (MFMA): 1x1 projection (unchanged from round 6). Output f32.
// ---------------------------------------------------------------------------
__global__ __launch_bounds__(256) void k_projm(
    const u16* __restrict__ bn, const float* __restrict__ wp, float* __restrict__ out)
{
  const int tid = threadIdx.x, nb = blockIdx.x;
  const int oh = nb & 1;
  const int pb = nb >> 1;            // 0..1023
  const int b  = pb >> 9;
  const int px0 = (pb & 511) << 7;   // 128-px slab (linear in NCHW plane)
  const int lane = tid & 63, wid = tid >> 6;
  const int wo = (wid >> 1) * 64, wpx = (wid & 1) * 64;
  const int n = lane & 31, h5 = lane >> 5;
  const int ob = oh * 128;
  const int pxl = px0 + wpx + n;

  f32x16 acc[2][2];
#pragma unroll
  for (int mt = 0; mt < 2; ++mt)
#pragma unroll
    for (int nt = 0; nt < 2; ++nt)
#pragma unroll
      for (int i = 0; i < 16; ++i) acc[mt][nt][i] = 0.f;

  const u16* bnb = bn + (size_t)b * C_ * HW_;
#pragma unroll 2
  for (int cb = 0; cb < 16; ++cb) {
    const int c0 = cb * 16;
    bf16x8 a[2];
#pragma unroll
    for (int mt = 0; mt < 2; ++mt) {
      const int row = ob + wo + mt * 32 + n;
      const float4 w0v = *(const float4*)&wp[(size_t)row * 256 + c0 + h5 * 8];
      const float4 w1v = *(const float4*)&wp[(size_t)row * 256 + c0 + h5 * 8 + 4];
      union { u32 u[4]; bf16x8 v; } T;
      T.u[0] = pack2rn(w0v.x, w0v.y);
      T.u[1] = pack2rn(w0v.z, w0v.w);
      T.u[2] = pack2rn(w1v.x, w1v.y);
      T.u[3] = pack2rn(w1v.z, w1v.w);
      a[mt] = T.v;
    }
    bf16x8 bb[2];
#pragma unroll
    for (int nt = 0; nt < 2; ++nt) {
      const u16* sp = bnb + (size_t)(c0 + h5 * 8) * HW_ + (pxl + nt * 32);
      const u32 e0 = sp[0 * HW_], e1 = sp[1 * HW_], e2 = sp[2 * HW_], e3 = sp[3 * HW_];
      const u32 e4 = sp[4 * HW_], e5 = sp[5 * HW_], e6 = sp[6 * HW_], e7 = sp[7 * HW_];
      union { u32 u[4]; bf16x8 v; } T;
      T.u[0] = e0 | (e1 << 16);
      T.u[1] = e2 | (e3 << 16);
      T.u[2] = e4 | (e5 << 16);
      T.u[3] = e6 | (e7 << 16);
      bb[nt] = T.v;
    }
    acc[0][0] = __builtin_amdgcn_mfma_f32_32x32x16_bf16(a[0], bb[0], acc[0][0], 0, 0, 0);
    acc[0][1] = __builtin_amdgcn_mfma_f32_32x32x16_bf16(a[0], bb[1], acc[0][1], 0, 0, 0);
    acc[1][0] = __builtin_amdgcn_mfma_f32_32x32x16_bf16(a[1], bb[0], acc[1][0], 0, 0, 0);
    acc[1][1] = __builtin_amdgcn_mfma_f32_32x32x16_bf16(a[1], bb[1], acc[1][1], 0, 0, 0);
  }
#pragma unroll
  for (int mt = 0; mt < 2; ++mt)
#pragma unroll
    for (int nt = 0; nt < 2; ++nt)
#pragma unroll
      for (int r = 0; r < 16; ++r) {
        const int o = ob + wo + mt * 32 + (r & 3) + 8 * (r >> 2) + 4 * h5;
        out[((size_t)(b * C_ + o)) * HW_ + (pxl + nt * 32)] = acc[mt][nt][r];
      }
}

// ---------------------------------------------------------------------------
extern "C" void kernel_launch(void* const* d_in, const int* in_sizes, int n_in,
                              void* d_out, int out_size, void* d_ws, size_t ws_size,
                              hipStream_t stream)
{
  const float* x     = (const float*)d_in[0];
  const float* wqkv  = (const float*)d_in[1];
  const float* rel   = (const float*)d_in[2];
  const float* wax   = (const float*)d_in[3];
  const float* bax   = (const float*)d_in[4];
  const float* way   = (const float*)d_in[5];
  const float* bay   = (const float*)d_in[6];
  const float* wdw   = (const float*)d_in[7];
  const float* gam   = (const float*)d_in[8];
  const float* bet   = (const float*)d_in[9];
  const float* mea   = (const float*)d_in[10];
  const float* var   = (const float*)d_in[11];
  const float* wproj = (const float*)d_in[12];
  float* out = (float*)d_out;

  const size_t N = (size_t)B_ * C_ * H_ * W_;
  u16* oNHWC  = (u16*)d_out;        // bf16 o, NHWC (first half of f32 out)
  u16* out1b  = (u16*)d_out + N;    // bf16 out1, NCHW (second half)
  u16* wtbuf  = (u16*)d_ws;         // WT 2MB + w8 384KB (bf16)
  float* biasT = (float*)((char*)d_ws + 2490368);  // 256KB, after WT+w8
  u16* bnbuf  = (u16*)d_ws;         // bn NCHW bf16 (reuses region after K2)

  hipLaunchKernelGGL(k_wt,     dim3(256),  dim3(256), 0, stream, wax, way, wqkv, rel, wtbuf, biasT);
  hipLaunchKernelGGL(k_attn,   dim3(2048), dim3(256), 0, stream, x, wtbuf + 1048576, biasT, oNHWC);
  hipLaunchKernelGGL(k_conv2m, dim3(1024), dim3(512), 0, stream, oNHWC, wtbuf, bax, bay, out1b);
  hipLaunchKernelGGL(k_dwbn,   dim3(8192), dim3(256), 0, stream, out1b, wdw, gam, bet, mea, var, bnbuf);
  hipLaunchKernelGGL(k_projm,  dim3(2048), dim3(256), 0, stream, bnbuf, wproj, out);
}

// Round 4
// 967.774 us; speedup vs baseline: 2.3964x; 1.2632x over previous
//
#include <hip/hip_runtime.h>
#include <stdint.h>

// GlobalAttention fused pipeline, MI355X gfx950.
// Round 8: k_conv2m -- each wave computes BOTH output rows (A-frag reuse 2x,
// 128-VGPR acc), 256 threads / 4 waves, launch_bounds(256,2) to lift VGPR cap,
// 2 blocks/CU co-resident, XCD-aware block swizzle for halo/WT L2 locality.
//   K0: wx,wy -> WT bf16; wqkv -> w8 bf16 [768][256]; rel -> biasT[16][64][64] f32
//   K1: x -> xb LDS once; MFMA qkv GEMM (head-remapped); per-wave attention
//   K2: o,WT -> out1 NCHW bf16 [MFMA, 2 rows/block, 2-row waves]
//   K3: out1 -> bn NCHW bf16 @ d_ws
//   K4: bn -> d_out f32 final [MFMA]

#define B_ 2
#define C_ 256
#define H_ 256
#define W_ 256
#define HW_ 65536

typedef unsigned short u16;
typedef unsigned int u32;
typedef short bf16x8 __attribute__((ext_vector_type(8)));
typedef float f32x4 __attribute__((ext_vector_type(4)));
typedef float f32x16 __attribute__((ext_vector_type(16)));

__device__ __forceinline__ float b2f(u16 h) {
  union { u32 u; float f; } x; x.u = ((u32)h) << 16; return x.f;
}
__device__ __forceinline__ float b2f_lo(u32 u) {
  union { u32 v; float f; } x; x.v = u << 16; return x.f;
}
__device__ __forceinline__ float b2f_hi(u32 u) {
  union { u32 v; float f; } x; x.v = u & 0xffff0000u; return x.f;
}
__device__ __forceinline__ u16 f2b(float f) {  // RNE
  union { float f; u32 u; } x; x.f = f;
  return (u16)((x.u + 0x7fffu + ((x.u >> 16) & 1u)) >> 16);
}
__device__ __forceinline__ u32 pack2(float a, float b) {
  return (u32)f2b(a) | ((u32)f2b(b) << 16);
}
// fast round-half-up bf16 pack: 3 ops via v_perm
__device__ __forceinline__ u32 pack2rn(float a, float b) {
  u32 ua = __float_as_uint(a) + 0x8000u;
  u32 ub = __float_as_uint(b) + 0x8000u;
  return __builtin_amdgcn_perm(ub, ua, 0x07060302u);
}
__device__ __forceinline__ u16 f2brn(float f) {
  return (u16)((__float_as_uint(f) + 0x8000u) >> 16);
}

// ---------------------------------------------------------------------------
// K0: WT bf16 [conv][t][o][c]; wqkv -> w8 bf16 [768][256];
//     rel -> biasT[head][j][i] f32 (16*64*64)
// ---------------------------------------------------------------------------
__global__ __launch_bounds__(256) void k_wt(
    const float* __restrict__ wx, const float* __restrict__ wy,
    const float* __restrict__ wqkv, const float* __restrict__ rel,
    u16* __restrict__ wt, float* __restrict__ biasT)
{
  const int o = blockIdx.x, c = threadIdx.x;
  const float* px = wx + ((size_t)o * 256 + c) * 8;
  const float* py = wy + ((size_t)o * 256 + c) * 8;
#pragma unroll
  for (int t = 0; t < 8; ++t) {
    wt[(size_t)t * 65536 + o * 256 + c]          = f2b(px[t]);
    wt[524288 + (size_t)t * 65536 + o * 256 + c] = f2b(py[t]);
  }
  u16* w8 = wt + 1048576;
#pragma unroll
  for (int t = 0; t < 3; ++t) {
    const int row = o + t * 256;
    w8[(size_t)row * 256 + c] = f2b(wqkv[(size_t)row * 256 + c]);
  }
  // biasT[h][j][i] = rel[ridx(i,j)*16+h]
  const int flat = o * 256 + c;
  const int h = flat >> 12, j = (flat >> 6) & 63, i = flat & 63;
  const int iy = i >> 3, ix = i & 7, jy = j >> 3, jx = j & 7;
  const int ridx = (iy - jy + 7) * 15 + (ix - jx + 7);
  biasT[flat] = rel[ridx * 16 + h];
}

// ---------------------------------------------------------------------------
// K1: qkv (MFMA) + windowed attention (per-wave, barrier-free phase 3).
// Wave w owns heads 4w..4w+3 (q/k/v channels 64w..64w+63).
// ---------------------------------------------------------------------------
__global__ __launch_bounds__(256) void k_attn(
    const float* __restrict__ x, const u16* __restrict__ w8,
    const float* __restrict__ biasT, u16* __restrict__ o_img)
{
  __shared__ __align__(16) union {
    u16 xb[64][264];   // phase 1-2: x window [px][c] bf16
    u16 P[4][4096];    // phase 3: per-wave P tile [i][j], XOR-swizzled
  } U;
  __shared__ __align__(16) u16 q_s[64][264];   // [px][ch], q pre-scaled 0.25
  __shared__ __align__(16) u16 k_s[64][264];   // [px][ch]
  __shared__ __align__(16) u16 v_sT[256][72];  // [ch][px]

  const int tid = threadIdx.x;
  const int nb  = blockIdx.x;
  const int b   = nb >> 10;
  const int hh  = (nb >> 5) & 31;
  const int ww  = nb & 31;
  const int h0  = hh << 3, w0 = ww << 3;

  // ---- phase 1: stage x window -> xb [px][c] bf16 ----
  {
    const int c2 = tid & 127;
    const int half = tid >> 7;
    const float* p0 = x + (((size_t)(b * C_ + 2 * c2)) * H_ + (h0 + half * 4)) * W_ + w0;
    const float* p1 = p0 + (size_t)H_ * W_;
#pragma unroll
    for (int r = 0; r < 4; ++r) {
      const float4 a0 = *(const float4*)(p0 + r * W_);
      const float4 a1 = *(const float4*)(p0 + r * W_ + 4);
      const float4 b0 = *(const float4*)(p1 + r * W_);
      const float4 b1 = *(const float4*)(p1 + r * W_ + 4);
      const float fa[8] = {a0.x, a0.y, a0.z, a0.w, a1.x, a1.y, a1.z, a1.w};
      const float fb[8] = {b0.x, b0.y, b0.z, b0.w, b1.x, b1.y, b1.z, b1.w};
      const int px0 = (half * 4 + r) * 8;
#pragma unroll
      for (int cc = 0; cc < 8; ++cc)
        *(u32*)&U.xb[px0 + cc][2 * c2] = pack2rn(fa[cc], fb[cc]);
    }
  }
  __syncthreads();

  // ---- phase 2: MFMA GEMM, wave w computes rows for its own heads ----
  const int lane = tid & 63, wid = tid >> 6;
  const int n = lane & 31, h5 = lane >> 5;

  f32x16 acc[6][2];
#pragma unroll
  for (int mt = 0; mt < 6; ++mt)
#pragma unroll
    for (int nt = 0; nt < 2; ++nt)
#pragma unroll
      for (int i = 0; i < 16; ++i) acc[mt][nt][i] = 0.f;

#pragma unroll 2
  for (int kb = 0; kb < 16; ++kb) {
    const int k0 = kb * 16;
    bf16x8 bfr[2];
#pragma unroll
    for (int nt = 0; nt < 2; ++nt) {
      union { uint4 u; bf16x8 v; } T;
      T.u = *(const uint4*)&U.xb[nt * 32 + n][k0 + h5 * 8];
      bfr[nt] = T.v;
    }
#pragma unroll
    for (int mt = 0; mt < 6; ++mt) {
      // q rows: wid*64.., k rows: 256+wid*64.., v rows: 512+wid*64..
      const int row = (mt >> 1) * 256 + wid * 64 + (mt & 1) * 32 + n;
      union { uint4 u; bf16x8 v; } A;
      A.u = *(const uint4*)(w8 + (size_t)row * 256 + k0 + h5 * 8);
      acc[mt][0] = __builtin_amdgcn_mfma_f32_32x32x16_bf16(A.v, bfr[0], acc[mt][0], 0, 0, 0);
      acc[mt][1] = __builtin_amdgcn_mfma_f32_32x32x16_bf16(A.v, bfr[1], acc[mt][1], 0, 0, 0);
    }
  }

  // ---- phase 2.5: scatter q,k -> [px][ch] (u32 pairs); v -> [ch][px] ----
  const int chb0 = wid * 64 + 4 * h5;
#pragma unroll
  for (int mt = 0; mt < 4; ++mt) {
    u16 (*dst)[264] = (mt < 2) ? q_s : k_s;
    const float qs = (mt < 2) ? 0.25f : 1.0f;
    const int chb = chb0 + (mt & 1) * 32;
#pragma unroll
    for (int nt = 0; nt < 2; ++nt) {
      const int px = nt * 32 + n;
#pragma unroll
      for (int m = 0; m < 8; ++m) {
        const int ch = chb + ((2 * m) & 3) + 8 * (m >> 1);
        *(u32*)&dst[px][ch] =
            pack2rn(acc[mt][nt][2 * m] * qs, acc[mt][nt][2 * m + 1] * qs);
      }
    }
  }
#pragma unroll
  for (int mt = 4; mt < 6; ++mt) {
    const int chb = chb0 + (mt & 1) * 32;
#pragma unroll
    for (int nt = 0; nt < 2; ++nt) {
      const int px = nt * 32 + n;
#pragma unroll
      for (int r = 0; r < 16; ++r) {
        const int ch = chb + (r & 3) + 8 * (r >> 2);
        v_sT[ch][px] = f2brn(acc[mt][nt][r]);
      }
    }
  }
  __syncthreads();  // protect xb->P union across all waves

  // ---- phase 3: per-wave attention, 4 heads, no barriers ----
  u16* Pw = U.P[wid];
  const int il = lane & 15, jg = lane >> 4;

  for (int hl = 0; hl < 4; ++hl) {
    const int head = wid * 4 + hl;
    const int hb = head * 16;

    // QK^T swapped: S^T[j][i] = K[j][d] . Q^T[d][i]   (scale folded into q)
    bf16x8 ak[2], bq[2];
#pragma unroll
    for (int jt = 0; jt < 2; ++jt) {
      union { uint4 u; bf16x8 v; } T;
      T.u = *(const uint4*)&k_s[jt * 32 + n][hb + h5 * 8];
      ak[jt] = T.v;
    }
#pragma unroll
    for (int it = 0; it < 2; ++it) {
      union { uint4 u; bf16x8 v; } T;
      T.u = *(const uint4*)&q_s[it * 32 + n][hb + h5 * 8];
      bq[it] = T.v;
    }
    f32x16 zro;
#pragma unroll
    for (int e = 0; e < 16; ++e) zro[e] = 0.f;
    f32x16 s[2][2];
#pragma unroll
    for (int jt = 0; jt < 2; ++jt)
#pragma unroll
      for (int it = 0; it < 2; ++it)
        s[jt][it] = __builtin_amdgcn_mfma_f32_32x32x16_bf16(ak[jt], bq[it], zro, 0, 0, 0);

    // + bias (biasT[head][j][i], coalesced over i = lanes)
    const float* bT = biasT + head * 4096;
#pragma unroll
    for (int jt = 0; jt < 2; ++jt)
#pragma unroll
      for (int it = 0; it < 2; ++it)
#pragma unroll
        for (int r = 0; r < 16; ++r) {
          const int j = jt * 32 + (r & 3) + 8 * (r >> 2) + 4 * h5;
          s[jt][it][r] += bT[j * 64 + it * 32 + n];
        }

    // in-lane softmax per i-row (lane pair n, n+32 holds the two j-halves)
#pragma unroll
    for (int it = 0; it < 2; ++it) {
      const int i = it * 32 + n;
      float mx = s[0][it][0];
#pragma unroll
      for (int jt = 0; jt < 2; ++jt)
#pragma unroll
        for (int r = 0; r < 16; ++r) mx = fmaxf(mx, s[jt][it][r]);
      mx = fmaxf(mx, __shfl_xor(mx, 32));
      float sum = 0.f;
#pragma unroll
      for (int jt = 0; jt < 2; ++jt)
#pragma unroll
        for (int r = 0; r < 16; ++r) {
          const float p = __expf(s[jt][it][r] - mx);
          s[jt][it][r] = p;
          sum += p;
        }
      sum += __shfl_xor(sum, 32);
      const float rs = 1.0f / sum;
      const u32 rowoff = (u32)(i * 128);
      const u32 swz = (u32)((i & 7) << 4);
#pragma unroll
      for (int jt = 0; jt < 2; ++jt)
#pragma unroll
        for (int m = 0; m < 8; ++m) {
          const int j = jt * 32 + ((2 * m) & 3) + 8 * (m >> 1) + 4 * h5;
          const u32 off = (rowoff + (u32)(j * 2)) ^ swz;
          *(u32*)((char*)Pw + off) =
              pack2rn(s[jt][it][2 * m] * rs, s[jt][it][2 * m + 1] * rs);
        }
    }

    // PV: O[64i][16d] = P[64x64] . V[64x16]  (16x16x32, N = d = 16 exactly)
    bf16x8 bv[2];
#pragma unroll
    for (int ks = 0; ks < 2; ++ks) {
      union { uint4 u; bf16x8 v; } T;
      T.u = *(const uint4*)&v_sT[hb + il][ks * 32 + jg * 8];
      bv[ks] = T.v;
    }
#pragma unroll
    for (int it2 = 0; it2 < 4; ++it2) {
      f32x4 pv = {0.f, 0.f, 0.f, 0.f};
#pragma unroll
      for (int ks = 0; ks < 2; ++ks) {
        const int i = it2 * 16 + il;
        const u32 off =
            ((u32)(i * 128 + ks * 64 + jg * 16)) ^ ((u32)((i & 7) << 4));
        union { uint4 u; bf16x8 v; } A;
        A.u = *(const uint4*)((const char*)Pw + off);
        pv = __builtin_amdgcn_mfma_f32_16x16x32_bf16(A.v, bv[ks], pv, 0, 0, 0);
      }
#pragma unroll
      for (int rr = 0; rr < 4; ++rr) {
        const int i = it2 * 16 + jg * 4 + rr;
        const int iy = i >> 3, ix = i & 7;
        o_img[(((size_t)(b * H_ + h0 + iy)) * W_ + (w0 + ix)) * C_ + hb + il] =
            f2brn(pv[rr]);
      }
    }
  }
}

// ---------------------------------------------------------------------------
// K2 (MFMA): out1 = ox + oy + bx + by.
// Round 8: 256 threads / 4 waves; each wave owns a 64o x 64w quadrant and
// computes BOTH output rows (acc[2][2][2], A-frags reused 2x). launch_bounds
// (256,2) lifts VGPR cap to 256; 2 blocks/CU co-resident (LDS 49.5 KB).
// XCD-aware bijective swizzle: contiguous hg chunks per XCD for halo/WT L2.
// ---------------------------------------------------------------------------
__global__ __launch_bounds__(256, 2) void k_conv2m(
    const u16* __restrict__ o_nhwc, const u16* __restrict__ wt,
    const float* __restrict__ bxg, const float* __restrict__ byg,
    u16* __restrict__ out1)
{
  __shared__ u16 tile[9 * 136 * 20];   // 47.8 KB
  __shared__ float bias_l[128];

  const int tid = threadIdx.x;
  // XCD swizzle: 1024 blocks = 8 XCDs x 128 contiguous ids (bijective)
  const int nb = (blockIdx.x & 7) * 128 + (blockIdx.x >> 3);
  const int wh = nb & 1, oh = (nb >> 1) & 1, hg = (nb >> 2) & 127, b = nb >> 9;
  const int h0 = hg << 1;             // 2 output rows h0, h0+1
  const int ob = oh * 128, wb0 = wh * 128;
  const int lane = tid & 63, wid = tid >> 6;
  const int o64 = (wid & 1) * 64;         // wave M-tile
  const int w64 = ((wid >> 1) & 1) * 64;  // wave N (w) tile
  const int n = lane & 31, h5 = lane >> 5;

  if (tid < 128) bias_l[tid] = bxg[ob + tid] + byg[ob + tid];

  f32x16 acc[2][2][2];   // [row][mt][nt]
#pragma unroll
  for (int r2 = 0; r2 < 2; ++r2)
#pragma unroll
    for (int mt = 0; mt < 2; ++mt)
#pragma unroll
      for (int nt = 0; nt < 2; ++nt)
#pragma unroll
        for (int i = 0; i < 16; ++i) acc[r2][mt][nt][i] = 0.f;

  for (int cb = 0; cb < 16; ++cb) {
    const int c0 = cb * 16;
    __syncthreads();
    // ---- stage 9 rows x 136 w x 16 c (NHWC source: 32B contiguous) ----
    for (int e = tid; e < 1224; e += 256) {
      const int r = e / 136, wi = e - r * 136;
      const int hp = h0 - 3 + r;
      const int wp = wb0 + wi - 4;
      uint2 v0 = make_uint2(0, 0), v1 = v0, v2 = v0, v3 = v0;
      if (hp >= 0 && hp <= 256 && wp >= 0 && wp <= 256) {
        const int hr = (hp == 256) ? 254 : hp;
        const int wr = (wp == 256) ? 254 : wp;
        const u16* src = o_nhwc + (((size_t)(b * H_ + hr)) * W_ + wr) * C_ + c0;
        const uint4 A  = *(const uint4*)src;
        const uint4 Bv = *(const uint4*)(src + 8);
        v0 = make_uint2(A.x, A.y);  v1 = make_uint2(A.z, A.w);
        v2 = make_uint2(Bv.x, Bv.y); v3 = make_uint2(Bv.z, Bv.w);
      }
      u16* d = &tile[(r * 136 + wi) * 20];
      *(uint2*)(d)      = v0;
      *(uint2*)(d + 4)  = v1;
      *(uint2*)(d + 8)  = v2;
      *(uint2*)(d + 12) = v3;
    }
    __syncthreads();
    // ---- compute: 2 convs x 8 taps, K=16 channels, BOTH rows per wave ----
#pragma unroll
    for (int cv = 0; cv < 2; ++cv) {
      const u16* wbase = wt + (size_t)cv * 524288;
#pragma unroll
      for (int t = 0; t < 8; ++t) {
        bf16x8 a[2];
#pragma unroll
        for (int mt = 0; mt < 2; ++mt) {
          const int o = ob + o64 + mt * 32 + n;
          union { uint4 u; bf16x8 v; } Uu;
          Uu.u = *(const uint4*)(wbase + ((size_t)(t * 256 + o)) * 256 + c0 + h5 * 8);
          a[mt] = Uu.v;
        }
        bf16x8 bb[2][2];   // [row][nt]
#pragma unroll
        for (int r2 = 0; r2 < 2; ++r2)
#pragma unroll
          for (int nt = 0; nt < 2; ++nt) {
            const int rr = cv ? (r2 + 3) : (r2 + t);
            const int wi = w64 + nt * 32 + n + (cv ? (t + 1) : 4);
            const u16* p = &tile[(rr * 136 + wi) * 20 + h5 * 8];
            union { uint2 u[2]; bf16x8 v; } Uu;
            Uu.u[0] = *(const uint2*)p;
            Uu.u[1] = *(const uint2*)(p + 4);
            bb[r2][nt] = Uu.v;
          }
#pragma unroll
        for (int r2 = 0; r2 < 2; ++r2) {
          acc[r2][0][0] = __builtin_amdgcn_mfma_f32_32x32x16_bf16(a[0], bb[r2][0], acc[r2][0][0], 0, 0, 0);
          acc[r2][0][1] = __builtin_amdgcn_mfma_f32_32x32x16_bf16(a[0], bb[r2][1], acc[r2][0][1], 0, 0, 0);
          acc[r2][1][0] = __builtin_amdgcn_mfma_f32_32x32x16_bf16(a[1], bb[r2][0], acc[r2][1][0], 0, 0, 0);
          acc[r2][1][1] = __builtin_amdgcn_mfma_f32_32x32x16_bf16(a[1], bb[r2][1], acc[r2][1][1], 0, 0, 0);
        }
      }
    }
  }
  // ---- epilogue: +bias, bf16, NCHW, both rows ----
#pragma unroll
  for (int r2 = 0; r2 < 2; ++r2)
#pragma unroll
    for (int mt = 0; mt < 2; ++mt)
#pragma unroll
      for (int nt = 0; nt < 2; ++nt)
#pragma unroll
        for (int r = 0; r < 16; ++r) {
          const int om = o64 + mt * 32 + (r & 3) + 8 * (r >> 2) + 4 * h5;
          const int o = ob + om;
          const int wg = wb0 + w64 + nt * 32 + n;
          const float v = acc[r2][mt][nt][r] + bias_l[om];
          out1[(((size_t)(b * C_ + o)) * H_ + (h0 + r2)) * W_ + wg] = f2b(v);
        }
}

// ---------------------------------------------------------------------------
// K3: depthwise 8x8 conv + BN (unchanged).
// ---------------------------------------------------------------------------
__global__ __launch_bounds__(256) void k_dwbn(
    const u16* __restrict__ out1, const float* __restrict__ wdw,
    const float* __restrict__ gam, const float* __restrict__ bet,
    const float* __restrict__ mea, const float* __restrict__ var,
    u16* __restrict__ bno)
{
  __shared__ u16 tile[23][264];
  const int tid = threadIdx.x, nb = blockIdx.x;
  const int c = nb & 255, ht = (nb >> 8) & 15, b = nb >> 12;
  const int h0 = ht * 16;

  for (int e = tid; e < 23 * 264; e += 256) {
    const int tr = e / 264, tc = e % 264;
    const int r = h0 - 3 + tr;
    const int cg = tc - 3;
    u16 v = 0;
    if (r >= 0 && r <= 256 && cg >= 0 && cg <= 256) {
      const int rr = (r == 256) ? 254 : r;
      const int cgm = (cg == 256) ? 254 : cg;
      v = out1[(((size_t)(b * C_ + c)) * H_ + rr) * W_ + cgm];
    }
    tile[tr][tc] = v;
  }
  float wk[64];
#pragma unroll
  for (int k2 = 0; k2 < 64; ++k2) wk[k2] = wdw[c * 64 + k2];
  const float scl = gam[c] / sqrtf(var[c] + 1e-5f);
  const float shf = bet[c] - mea[c] * scl;
  __syncthreads();

  const int wg = tid & 31, hg = tid >> 5;
  const int w0 = wg * 8;
#pragma unroll
  for (int k = 0; k < 2; ++k) {
    const int hl = hg * 2 + k;
    float a[8];
#pragma unroll
    for (int s = 0; s < 8; ++s) a[s] = 0.f;
#pragma unroll
    for (int i = 0; i < 8; ++i) {
      const uint4 va = *(const uint4*)&tile[hl + i][w0];
      const uint4 vb = *(const uint4*)&tile[hl + i][w0 + 8];
      float f[16];
      f[0] = b2f_lo(va.x);  f[1] = b2f_hi(va.x);  f[2] = b2f_lo(va.y);  f[3] = b2f_hi(va.y);
      f[4] = b2f_lo(va.z);  f[5] = b2f_hi(va.z);  f[6] = b2f_lo(va.w);  f[7] = b2f_hi(va.w);
      f[8] = b2f_lo(vb.x);  f[9] = b2f_hi(vb.x);  f[10] = b2f_lo(vb.y); f[11] = b2f_hi(vb.y);
      f[12] = b2f_lo(vb.z); f[13] = b2f_hi(vb.z); f[14] = b2f_lo(vb.w); f[15] = b2f_hi(vb.w);
#pragma unroll
      for (int j = 0; j < 8; ++j) {
        const float wv = wk[i * 8 + j];
#pragma unroll
        for (int s = 0; s < 8; ++s) a[s] += f[s + j] * wv;
      }
    }
    uint4 uv;
    uv.x = pack2(a[0] * scl + shf, a[1] * scl + shf);
    uv.y = pack2(a[2] * scl + shf, a[3] * scl + shf);
    uv.z = pack2(a[4] * scl + shf, a[5] * scl + shf);
    uv.w = pack2(a[6] * scl + shf, a[7] * scl + shf);
    *(uint4*)&bno[(((size_t)(b * C_ + c)) * H_ + h0 + hl) * W_ + w0] = uv;
  }
}

// ---------------------------------------------------------------------------
// K4 (MFMA): 1x1 projection (unchanged). Output f32.
// ---------------------------------------------------------------------------
__global__ __launch_bounds__(256) void k_projm(
    const u16* __restrict__ bn, const float* __restrict__ wp, float* __restrict__ out)
{
  const int tid = threadIdx.x, nb = blockIdx.x;
  const int oh = nb & 1;
  const int pb = nb >> 1;            // 0..1023
  const int b  = pb >> 9;
  const int px0 = (pb & 511) << 7;   // 128-px slab (linear in NCHW plane)
  const int lane = tid & 63, wid = tid >> 6;
  const int wo = (wid >> 1) * 64, wpx = (wid & 1) * 64;
  const int n = lane & 31, h5 = lane >> 5;
  const int ob = oh * 128;
  const int pxl = px0 + wpx + n;

  f32x16 acc[2][2];
#pragma unroll
  for (int mt = 0; mt < 2; ++mt)
#pragma unroll
    for (int nt = 0; nt < 2; ++nt)
#pragma unroll
      for (int i = 0; i < 16; ++i) acc[mt][nt][i] = 0.f;

  const u16* bnb = bn + (size_t)b * C_ * HW_;
#pragma unroll 2
  for (int cb = 0; cb < 16; ++cb) {
    const int c0 = cb * 16;
    bf16x8 a[2];
#pragma unroll
    for (int mt = 0; mt < 2; ++mt) {
      const int row = ob + wo + mt * 32 + n;
      const float4 w0v = *(const float4*)&wp[(size_t)row * 256 + c0 + h5 * 8];
      const float4 w1v = *(const float4*)&wp[(size_t)row * 256 + c0 + h5 * 8 + 4];
      union { u32 u[4]; bf16x8 v; } T;
      T.u[0] = pack2rn(w0v.x, w0v.y);
      T.u[1] = pack2rn(w0v.z, w0v.w);
      T.u[2] = pack2rn(w1v.x, w1v.y);
      T.u[3] = pack2rn(w1v.z, w1v.w);
      a[mt] = T.v;
    }
    bf16x8 bb[2];
#pragma unroll
    for (int nt = 0; nt < 2; ++nt) {
      const u16* sp = bnb + (size_t)(c0 + h5 * 8) * HW_ + (pxl + nt * 32);
      const u32 e0 = sp[0 * HW_], e1 = sp[1 * HW_], e2 = sp[2 * HW_], e3 = sp[3 * HW_];
      const u32 e4 = sp[4 * HW_], e5 = sp[5 * HW_], e6 = sp[6 * HW_], e7 = sp[7 * HW_];
      union { u32 u[4]; bf16x8 v; } T;
      T.u[0] = e0 | (e1 << 16);
      T.u[1] = e2 | (e3 << 16);
      T.u[2] = e4 | (e5 << 16);
      T.u[3] = e6 | (e7 << 16);
      bb[nt] = T.v;
    }
    acc[0][0] = __builtin_amdgcn_mfma_f32_32x32x16_bf16(a[0], bb[0], acc[0][0], 0, 0, 0);
    acc[0][1] = __builtin_amdgcn_mfma_f32_32x32x16_bf16(a[0], bb[1], acc[0][1], 0, 0, 0);
    acc[1][0] = __builtin_amdgcn_mfma_f32_32x32x16_bf16(a[1], bb[0], acc[1][0], 0, 0, 0);
    acc[1][1] = __builtin_amdgcn_mfma_f32_32x32x16_bf16(a[1], bb[1], acc[1][1], 0, 0, 0);
  }
#pragma unroll
  for (int mt = 0; mt < 2; ++mt)
#pragma unroll
    for (int nt = 0; nt < 2; ++nt)
#pragma unroll
      for (int r = 0; r < 16; ++r) {
        const int o = ob + wo + mt * 32 + (r & 3) + 8 * (r >> 2) + 4 * h5;
        out[((size_t)(b * C_ + o)) * HW_ + (pxl + nt * 32)] = acc[mt][nt][r];
      }
}

// ---------------------------------------------------------------------------
extern "C" void kernel_launch(void* const* d_in, const int* in_sizes, int n_in,
                              void* d_out, int out_size, void* d_ws, size_t ws_size,
                              hipStream_t stream)
{
  const float* x     = (const float*)d_in[0];
  const float* wqkv  = (const float*)d_in[1];
  const float* rel   = (const float*)d_in[2];
  const float* wax   = (const float*)d_in[3];
  const float* bax   = (const float*)d_in[4];
  const float* way   = (const float*)d_in[5];
  const float* bay   = (const float*)d_in[6];
  const float* wdw   = (const float*)d_in[7];
  const float* gam   = (const float*)d_in[8];
  const float* bet   = (const float*)d_in[9];
  const float* mea   = (const float*)d_in[10];
  const float* var   = (const float*)d_in[11];
  const float* wproj = (const float*)d_in[12];
  float* out = (float*)d_out;

  const size_t N = (size_t)B_ * C_ * H_ * W_;
  u16* oNHWC  = (u16*)d_out;        // bf16 o, NHWC (first half of f32 out)
  u16* out1b  = (u16*)d_out + N;    // bf16 out1, NCHW (second half)
  u16* wtbuf  = (u16*)d_ws;         // WT 2MB + w8 384KB (bf16)
  float* biasT = (float*)((char*)d_ws + 2490368);  // 256KB, after WT+w8
  u16* bnbuf  = (u16*)d_ws;         // bn NCHW bf16 (reuses region after K2)

  hipLaunchKernelGGL(k_wt,     dim3(256),  dim3(256), 0, stream, wax, way, wqkv, rel, wtbuf, biasT);
  hipLaunchKernelGGL(k_attn,   dim3(2048), dim3(256), 0, stream, x, wtbuf + 1048576, biasT, oNHWC);
  hipLaunchKernelGGL(k_conv2m, dim3(1024), dim3(256), 0, stream, oNHWC, wtbuf, bax, bay, out1b);
  hipLaunchKernelGGL(k_dwbn,   dim3(8192), dim3(256), 0, stream, out1b, wdw, gam, bet, mea, var, bnbuf);
  hipLaunchKernelGGL(k_projm,  dim3(2048), dim3(256), 0, stream, bnbuf, wproj, out);
}